// Round 8
// baseline (823.432 us; speedup 1.0000x reference)
//
#include <hip/hip_runtime.h>

#define CDIM 128
#define NGRAPH 256
#define BSH 7                 // 128 nodes per bucket
#define BCAP 4096             // LDS sort capacity (mean 2048, +45 sigma)
#define NBLK 256              // blocks for two-pass scatter
#define PCHUNK 512            // nodes per pooling block

typedef unsigned short bf16_t;
typedef __attribute__((ext_vector_type(8))) short bf16x8;  // MFMA A/B frag (4 VGPRs)
typedef __attribute__((ext_vector_type(4))) float f32x4;   // MFMA C/D frag

__device__ __forceinline__ float bflo(unsigned u) { return __uint_as_float(u << 16); }
__device__ __forceinline__ float bfhi(unsigned u) { return __uint_as_float(u & 0xffff0000u); }
__device__ __forceinline__ unsigned short f2bf(float f) {
  unsigned u = __float_as_uint(f);
  u += 0x7fffu + ((u >> 16) & 1u);   // round-to-nearest-even
  return (unsigned short)(u >> 16);
}

// ---------- generic block-sum + scan kernels (for phist) ----------
__global__ __launch_bounds__(1024) void k_bsum(const int* __restrict__ counts,
    int* __restrict__ bsums, int N) {
  __shared__ int wsum[16];
  int tid = threadIdx.x;
  int base = blockIdx.x * 4096 + tid * 4;
  int4 c = make_int4(0, 0, 0, 0);
  if (base + 3 < N) c = *(const int4*)&counts[base];
  else {
    if (base + 0 < N) c.x = counts[base + 0];
    if (base + 1 < N) c.y = counts[base + 1];
    if (base + 2 < N) c.z = counts[base + 2];
  }
  int s = c.x + c.y + c.z + c.w;
#pragma unroll
  for (int ofs = 32; ofs > 0; ofs >>= 1) s += __shfl_down(s, ofs, 64);
  if ((tid & 63) == 0) wsum[tid >> 6] = s;
  __syncthreads();
  if (tid == 0) {
    int t = 0;
#pragma unroll
    for (int i = 0; i < 16; i++) t += wsum[i];
    bsums[blockIdx.x] = t;
  }
}

__global__ __launch_bounds__(1024) void k_boff(const int* __restrict__ bsums,
    int* __restrict__ boffs, int G) {
  __shared__ int sh[1024];
  int tid = threadIdx.x;
  int v = (tid < G) ? bsums[tid] : 0;
  sh[tid] = v;
  __syncthreads();
  for (int ofs = 1; ofs < 1024; ofs <<= 1) {
    int u = (tid >= ofs) ? sh[tid - ofs] : 0;
    __syncthreads();
    sh[tid] += u;
    __syncthreads();
  }
  if (tid < G) boffs[tid] = sh[tid] - v;
  if (tid == G) boffs[G] = (G > 0) ? sh[G - 1] : 0;
}

// generic exclusive-scan tile kernel (offsets only)
__global__ __launch_bounds__(1024) void k_scan3(const int* __restrict__ counts,
    const int* __restrict__ boffs, int* __restrict__ offs, int M) {
  __shared__ int wsum[16];
  int tid = threadIdx.x;
  int lane = tid & 63, wave = tid >> 6;
  int base = blockIdx.x * 4096 + tid * 4;
  int4 c = make_int4(0, 0, 0, 0);
  if (base + 3 < M) c = *(const int4*)&counts[base];
  else {
    if (base + 0 < M) c.x = counts[base + 0];
    if (base + 1 < M) c.y = counts[base + 1];
    if (base + 2 < M) c.z = counts[base + 2];
  }
  int tsum = c.x + c.y + c.z + c.w;
  int v = tsum;
#pragma unroll
  for (int ofs = 1; ofs < 64; ofs <<= 1) {
    int u = __shfl_up(v, ofs, 64);
    if (lane >= ofs) v += u;
  }
  if (lane == 63) wsum[wave] = v;
  __syncthreads();
  if (wave == 0) {
    int w = (lane < 16) ? wsum[lane] : 0;
#pragma unroll
    for (int ofs = 1; ofs < 16; ofs <<= 1) {
      int u = __shfl_up(w, ofs, 64);
      if (lane >= ofs) w += u;
    }
    if (lane < 16) wsum[lane] = w;
  }
  __syncthreads();
  int waveoff = (wave == 0) ? 0 : wsum[wave - 1];
  int excl = boffs[blockIdx.x] + waveoff + (v - tsum);
  int r[4]; r[0] = excl; r[1] = r[0] + c.x; r[2] = r[1] + c.y; r[3] = r[2] + c.z;
#pragma unroll
  for (int k = 0; k < 4; k++) {
    int idx = base + k;
    if (idx < M) offs[idx] = r[k];
  }
}

// pass A: per-block LDS histogram over buckets -> phist[bucket*NBLK + blk]
__global__ __launch_bounds__(1024) void k_phist(const int* __restrict__ dst,
    int* __restrict__ phist, int E, int NB) {
  __shared__ int hist[1024];
  int t = blockIdx.x, tid = threadIdx.x;
  for (int i = tid; i < NB; i += 1024) hist[i] = 0;
  __syncthreads();
  int tile = (E + NBLK - 1) / NBLK;
  int lo = t * tile;
  int hi = lo + tile; if (hi > E) hi = E;
  for (int i = lo + tid; i < hi; i += 1024) atomicAdd(&hist[dst[i] >> BSH], 1);
  __syncthreads();
  for (int i = tid; i < NB; i += 1024) phist[i * NBLK + t] = hist[i];
}

// pass B: exact-offset scatter, LDS cursors, zero global atomics.
__global__ __launch_bounds__(1024) void k_pscatter(const int* __restrict__ src,
    const int* __restrict__ dst, const int* __restrict__ poff,
    unsigned* __restrict__ tmp, int E, int NB) {
  __shared__ int cur[1024];
  int t = blockIdx.x, tid = threadIdx.x;
  for (int i = tid; i < NB; i += 1024) cur[i] = poff[i * NBLK + t];
  __syncthreads();
  int tile = (E + NBLK - 1) / NBLK;
  int lo = t * tile;
  int hi = lo + tile; if (hi > E) hi = E;
  for (int i = lo + tid; i < hi; i += 1024) {
    int d = dst[i];
    int p = atomicAdd(&cur[d >> BSH], 1);
    tmp[p] = (unsigned)src[i] | ((unsigned)(d & 127) << 20);
  }
}

// pass C: per-bucket LDS histogram + scan + counting sort.
__global__ __launch_bounds__(256) void k_csort2(const unsigned* __restrict__ tmp,
    const int* __restrict__ poff, int* __restrict__ rowptr, float* __restrict__ dinv,
    int* __restrict__ col, int N, int NB, int E) {
  __shared__ int hist[128];
  __shared__ int sc[128];
  __shared__ int lcur[128];
  __shared__ unsigned buf[BCAP];
  int b = blockIdx.x;
  int n0 = b << BSH;
  int base = poff[(size_t)b * NBLK];
  int nxt = (b + 1 < NB) ? poff[(size_t)(b + 1) * NBLK] : E;
  int cnt = nxt - base;
  int tid = threadIdx.x;
  if (tid < 128) hist[tid] = 0;
  __syncthreads();
  for (int i = tid; i < cnt; i += 256) atomicAdd(&hist[(tmp[base + i] >> 20) & 127], 1);
  __syncthreads();
  if (tid < 128) sc[tid] = hist[tid];
  __syncthreads();
  for (int ofs = 1; ofs < 128; ofs <<= 1) {
    int v = (tid < 128 && tid >= ofs) ? sc[tid - ofs] : 0;
    __syncthreads();
    if (tid < 128) sc[tid] += v;
    __syncthreads();
  }
  if (tid < 128) {
    int excl = sc[tid] - hist[tid];
    lcur[tid] = excl;
    int node = n0 + tid;
    if (node < N) {
      rowptr[node] = base + excl;
      dinv[node] = rsqrtf((float)hist[tid] + 1.0f);
    }
  }
  if (b == 0 && tid == 0) rowptr[N] = E;
  __syncthreads();
  if (cnt <= BCAP) {
    for (int i = tid; i < cnt; i += 256) {
      unsigned pk = tmp[base + i];
      int p = atomicAdd(&lcur[(pk >> 20) & 127], 1);
      buf[p] = pk & 0xFFFFFu;
    }
    __syncthreads();
    for (int i = tid; i < cnt; i += 256) col[base + i] = (int)buf[i];
  } else {
    for (int i = tid; i < cnt; i += 256) {
      unsigned pk = tmp[base + i];
      int p = atomicAdd(&lcur[(pk >> 20) & 127], 1);
      col[base + p] = (int)(pk & 0xFFFFFu);
    }
  }
}

// ---------- MFMA GEMM: [M x 128] @ [128 x 128], bf16 MFMA, fp32 acc ----------
// Output is CHANNEL-BLOCKED: 8 planes of [M x 16ch]; D-tile t -> plane t.
// BF16IN=0: A fp32 row-major; BF16IN=1: A is channel-blocked bf16 planes.
#define WSTRIDE 136
template <int BF16IN>
__global__ __launch_bounds__(256) void k_gemm(const void* __restrict__ Ap,
    const float* __restrict__ W, bf16_t* __restrict__ Co, int M) {
  __shared__ bf16_t Wt[128 * WSTRIDE];
  int tid = threadIdx.x;
  for (int i = tid; i < 4096; i += 256) {
    int k = i >> 5;
    int nq = (i & 31) << 2;
    float4 w = *(const float4*)&W[k * CDIM + nq];
    Wt[(nq + 0) * WSTRIDE + k] = f2bf(w.x);
    Wt[(nq + 1) * WSTRIDE + k] = f2bf(w.y);
    Wt[(nq + 2) * WSTRIDE + k] = f2bf(w.z);
    Wt[(nq + 3) * WSTRIDE + k] = f2bf(w.w);
  }
  __syncthreads();

  int wave = tid >> 6;
  int lane = tid & 63;
  int m = lane & 15;
  int q = lane >> 4;
  int nstrips = (M + 63) >> 6;

  for (int s = blockIdx.x; s < nstrips; s += gridDim.x) {
    int rowA = s * 64 + wave * 16 + m;
    if (rowA > M - 1) rowA = M - 1;
    bf16x8 a[4];
#pragma unroll
    for (int c = 0; c < 4; c++) {
      if (BF16IN) {
        // channels c*32 + q*8 .. +8 live in plane p = 2c + (q>>1), offset (q&1)*8
        const bf16_t* hp = (const bf16_t*)Ap;
        int pl = 2 * c + (q >> 1);
        a[c] = *(const bf16x8*)(hp + ((size_t)pl * M + rowA) * 16 + (q & 1) * 8);
      } else {
        const float* ap = (const float*)Ap + (size_t)rowA * CDIM + c * 32 + q * 8;
        float4 f0 = *(const float4*)ap;
        float4 f1 = *(const float4*)(ap + 4);
        union { bf16x8 v; unsigned short u[8]; } ua;
        ua.u[0] = f2bf(f0.x); ua.u[1] = f2bf(f0.y); ua.u[2] = f2bf(f0.z); ua.u[3] = f2bf(f0.w);
        ua.u[4] = f2bf(f1.x); ua.u[5] = f2bf(f1.y); ua.u[6] = f2bf(f1.z); ua.u[7] = f2bf(f1.w);
        a[c] = ua.v;
      }
    }
#pragma unroll
    for (int t = 0; t < 8; t++) {
      f32x4 acc = {0.f, 0.f, 0.f, 0.f};
#pragma unroll
      for (int c = 0; c < 4; c++) {
        bf16x8 bv = *(const bf16x8*)&Wt[(t * 16 + m) * WSTRIDE + c * 32 + q * 8];
        acc = __builtin_amdgcn_mfma_f32_16x16x32_bf16(a[c], bv, acc, 0, 0, 0);
      }
#pragma unroll
      for (int r = 0; r < 4; r++) {
        int row = s * 64 + wave * 16 + q * 4 + r;
        if (row < M) Co[((size_t)t * M + row) * 16 + m] = f2bf(acc[r]);
      }
    }
  }
}

// ---------- channel-blocked gather aggregation + bias + relu ----------
// group g = blockIdx.x & 7 -> plane g (3.2 MB, fits one XCD L2 under round-robin
// dispatch). Wave = 8 edge-slots x 8 lanes (2ch/lane). 64-edge register preload,
// shfl broadcast, x2 unroll, butterfly slot-reduction.
__global__ __launch_bounds__(256) void k_agg2(const bf16_t* __restrict__ tcb,
    const int* __restrict__ rowptr, const int* __restrict__ col,
    const float* __restrict__ dinv, const float* __restrict__ bias,
    bf16_t* __restrict__ outcb, int N) {
  int tid = threadIdx.x;
  int wave = tid >> 6, lane = tid & 63;
  int g = blockIdx.x & 7;
  int node = (blockIdx.x >> 3) * 4 + wave;
  if (node >= N) return;
  int slot = lane >> 3;        // 0..7 edge slot
  int u = lane & 7;            // channel-pair index within plane
  const unsigned* plane = (const unsigned*)tcb + (size_t)g * N * 8;
  unsigned* opl = (unsigned*)outcb + (size_t)g * N * 8;
  float di = dinv[node];
  // self term, counted once (slot 0)
  unsigned su = plane[(size_t)node * 8 + u];
  float selfw = (slot == 0) ? di : 0.f;
  float ax = bflo(su) * selfw;
  float ay = bfhi(su) * selfw;
  int beg = rowptr[node], end = rowptr[node + 1];
  for (int base = beg; base < end; base += 64) {
    int rem = end - base;
    int cnt = rem < 64 ? rem : 64;
    int sL = 0; float wL = 0.f;
    if (lane < cnt) {
      sL = __builtin_nontemporal_load(&col[base + lane]);
      wL = dinv[sL];
    }
    for (int chunk = 0; chunk * 8 < cnt; chunk += 2) {
      int j0 = chunk * 8 + slot, j1 = j0 + 8;
      int s0 = __shfl(sL, j0, 64); float w0 = __shfl(wL, j0, 64);
      int s1 = __shfl(sL, j1, 64); float w1 = __shfl(wL, j1, 64);
      if (j0 >= cnt) { s0 = node; w0 = 0.f; }
      if (j1 >= cnt) { s1 = node; w1 = 0.f; }
      unsigned v0 = plane[(size_t)s0 * 8 + u];
      unsigned v1 = plane[(size_t)s1 * 8 + u];
      ax = fmaf(bflo(v0), w0, ax); ay = fmaf(bfhi(v0), w0, ay);
      ax = fmaf(bflo(v1), w1, ax); ay = fmaf(bfhi(v1), w1, ay);
    }
  }
#pragma unroll
  for (int ofs = 8; ofs < 64; ofs <<= 1) {
    ax += __shfl_xor(ax, ofs, 64);
    ay += __shfl_xor(ay, ofs, 64);
  }
  if (slot == 0) {
    float2 bb = ((const float2*)bias)[g * 8 + u];
    float ox = fmaxf(fmaf(di, ax, bb.x), 0.f);
    float oy = fmaxf(fmaf(di, ay, bb.y), 0.f);
    unsigned o = ((unsigned)f2bf(oy) << 16) | f2bf(ox);
    __builtin_nontemporal_store(o, &opl[(size_t)node * 8 + u]);
  }
}

// ---------- global mean pool over channel-blocked h ----------
__global__ __launch_bounds__(256) void k_pool2(const bf16_t* __restrict__ hcb,
    const int* __restrict__ batch, float* __restrict__ gsum, int N) {
  int tid = threadIdx.x;
  int wave = tid >> 6, lane = tid & 63;
  const unsigned* hu = (const unsigned*)hcb;
  int pl = lane >> 3, u = lane & 7;
  int c0 = pl * 16 + u * 2;
  int i0 = blockIdx.x * PCHUNK;
  int i1 = i0 + PCHUNK; if (i1 > N) i1 = N;
  float ax = 0.f, ay = 0.f;
  int curb = -1;
  for (int i = i0 + wave; i < i1; i += 4) {
    int b = batch[i];
    if (b != curb) {
      if (curb >= 0) {
        atomicAdd(&gsum[curb * CDIM + c0], ax);
        atomicAdd(&gsum[curb * CDIM + c0 + 1], ay);
      }
      curb = b; ax = 0.f; ay = 0.f;
    }
    unsigned uv = hu[((size_t)pl * N + i) * 8 + u];
    ax += bflo(uv); ay += bfhi(uv);
  }
  if (curb >= 0) {
    atomicAdd(&gsum[curb * CDIM + c0], ax);
    atomicAdd(&gsum[curb * CDIM + c0 + 1], ay);
  }
}

// divide by per-graph node count (binary search over sorted batch), in place.
__global__ __launch_bounds__(128) void k_pooldiv(float* __restrict__ g,
    const int* __restrict__ batch, int N) {
  int b = blockIdx.x;
  int lo = 0, hi = N;
  while (lo < hi) { int mid = (lo + hi) >> 1; if (batch[mid] < b) lo = mid + 1; else hi = mid; }
  int s = lo;
  lo = 0; hi = N;
  int key = b + 1;
  while (lo < hi) { int mid = (lo + hi) >> 1; if (batch[mid] < key) lo = mid + 1; else hi = mid; }
  float inv = 1.f / fmaxf((float)(lo - s), 1.f);
  g[b * CDIM + threadIdx.x] *= inv;
}

// ---------- MLP head ----------
__global__ __launch_bounds__(512) void k_mlp1(const float* __restrict__ g,
    const float* __restrict__ W, const float* __restrict__ b, float* __restrict__ o) {
  __shared__ float gs[CDIM];
  int bi = blockIdx.x, tid = threadIdx.x;
  if (tid < CDIM) gs[tid] = g[bi * CDIM + tid];
  __syncthreads();
  if (tid < 500) {
    float acc = b[tid];
#pragma unroll 4
    for (int k = 0; k < CDIM; k++) acc = fmaf(gs[k], W[k * 500 + tid], acc);
    o[bi * 500 + tid] = fmaxf(acc, 0.f);
  }
}

__global__ __launch_bounds__(128) void k_mlp2(const float* __restrict__ a,
    const float* __restrict__ W, const float* __restrict__ b, float* __restrict__ o) {
  __shared__ float as[500];
  int bi = blockIdx.x, tid = threadIdx.x;
  for (int k = tid; k < 500; k += 128) as[k] = a[bi * 500 + k];
  __syncthreads();
  if (tid < 100) {
    float acc = b[tid];
    for (int k = 0; k < 500; k++) acc = fmaf(as[k], W[k * 100 + tid], acc);
    o[bi * 100 + tid] = fmaxf(acc, 0.f);
  }
}

__global__ __launch_bounds__(64) void k_mlp3(const float* __restrict__ a,
    const float* __restrict__ w, const float* __restrict__ b, float* __restrict__ o) {
  int bi = blockIdx.x, lane = threadIdx.x;
  float v = a[bi * 100 + lane] * w[lane];
  if (lane + 64 < 100) v = fmaf(a[bi * 100 + lane + 64], w[lane + 64], v);
#pragma unroll
  for (int ofs = 32; ofs > 0; ofs >>= 1) v += __shfl_down(v, ofs, 64);
  if (lane == 0) o[bi] = v + b[0];
}

static inline size_t align_up(size_t v) { return (v + 255) & ~(size_t)255; }

extern "C" void kernel_launch(void* const* d_in, const int* in_sizes, int n_in,
                              void* d_out, int out_size, void* d_ws, size_t ws_size,
                              hipStream_t stream) {
  const float* x   = (const float*)d_in[0];
  const int*   ei  = (const int*)d_in[1];
  const int*   bat = (const int*)d_in[2];
  const float* W1  = (const float*)d_in[3];
  const float* b1  = (const float*)d_in[4];
  const float* W2  = (const float*)d_in[5];
  const float* b2  = (const float*)d_in[6];
  const float* Wm1 = (const float*)d_in[7];
  const float* bm1 = (const float*)d_in[8];
  const float* Wm2 = (const float*)d_in[9];
  const float* bm2 = (const float*)d_in[10];
  const float* Wm3 = (const float*)d_in[11];
  const float* bm3 = (const float*)d_in[12];
  float* out = (float*)d_out;

  const int E = in_sizes[1] / 2;
  const int N = in_sizes[2];
  const int* src = ei;
  const int* dst = ei + E;
  const int NB = (N + 127) >> BSH;
  const int M  = NB * NBLK;              // phist elements
  const int G2 = (M + 4095) / 4096;

  char* p = (char*)d_ws;
  bf16_t* t    = (bf16_t*)p;   p += align_up((size_t)N * CDIM * 2);
  bf16_t* h    = (bf16_t*)p;   p += align_up((size_t)N * CDIM * 2);
  int* rowptr  = (int*)p;      p += align_up((size_t)(N + 1) * 4);
  int* colx    = (int*)p;      p += align_up((size_t)E * 4);
  unsigned* tmp= (unsigned*)p; p += align_up((size_t)E * 4);
  float* dinv  = (float*)p;    p += align_up((size_t)N * 4);
  int* phist   = (int*)p;      p += align_up((size_t)M * 4);
  int* poff    = (int*)p;      p += align_up((size_t)M * 4);
  int* bsumsB  = (int*)p;      p += align_up((size_t)G2 * 4);
  int* boffsB  = (int*)p;      p += align_up((size_t)(G2 + 1) * 4);
  float* gb    = (float*)p;    p += align_up((size_t)NGRAPH * CDIM * 4);
  float* m1    = (float*)p;    p += align_up((size_t)NGRAPH * 500 * 4);
  float* m2    = (float*)p;    p += align_up((size_t)NGRAPH * 100 * 4);
  (void)ws_size; (void)n_in; (void)out_size;

  hipMemsetAsync(gb, 0, (size_t)NGRAPH * CDIM * 4, stream);

  k_phist<<<NBLK, 1024, 0, stream>>>(dst, phist, E, NB);
  k_bsum<<<G2, 1024, 0, stream>>>(phist, bsumsB, M);
  k_boff<<<1, 1024, 0, stream>>>(bsumsB, boffsB, G2);
  k_scan3<<<G2, 1024, 0, stream>>>(phist, boffsB, poff, M);
  k_pscatter<<<NBLK, 1024, 0, stream>>>(src, dst, poff, tmp, E, NB);
  k_csort2<<<NB, 256, 0, stream>>>(tmp, poff, rowptr, dinv, colx, N, NB, E);

  int nstrips = (N + 63) >> 6;
  int gblocks = nstrips < 1024 ? nstrips : 1024;
  int ablocks = 8 * ((N + 3) / 4);
  k_gemm<0><<<gblocks, 256, 0, stream>>>(x, W1, t, N);
  k_agg2<<<ablocks, 256, 0, stream>>>(t, rowptr, colx, dinv, b1, h, N);
  k_gemm<1><<<gblocks, 256, 0, stream>>>(h, W2, t, N);
  k_agg2<<<ablocks, 256, 0, stream>>>(t, rowptr, colx, dinv, b2, h, N);

  k_pool2<<<(N + PCHUNK - 1) / PCHUNK, 256, 0, stream>>>(h, bat, gb, N);
  k_pooldiv<<<NGRAPH, 128, 0, stream>>>(gb, bat, N);
  k_mlp1<<<NGRAPH, 512, 0, stream>>>(gb, Wm1, bm1, m1);
  k_mlp2<<<NGRAPH, 128, 0, stream>>>(m1, Wm2, bm2, m2);
  k_mlp3<<<NGRAPH, 64, 0, stream>>>(m2, Wm3, bm3, out);
}

// Round 9
// 410.578 us; speedup vs baseline: 2.0055x; 2.0055x over previous
//
#include <hip/hip_runtime.h>

#define CDIM 128
#define NGRAPH 256
#define BSH 7                 // 128 nodes per bucket
#define BCAP 4096             // LDS sort capacity (mean 2048, +45 sigma)
#define NBLK 256              // blocks for two-pass scatter
#define PCHUNK 512            // nodes per pooling block

typedef unsigned short bf16_t;
typedef __attribute__((ext_vector_type(8))) short bf16x8;  // MFMA A/B frag (4 VGPRs)
typedef __attribute__((ext_vector_type(4))) float f32x4;   // MFMA C/D frag

__device__ __forceinline__ float bflo(unsigned u) { return __uint_as_float(u << 16); }
__device__ __forceinline__ float bfhi(unsigned u) { return __uint_as_float(u & 0xffff0000u); }
__device__ __forceinline__ unsigned short f2bf(float f) {
  unsigned u = __float_as_uint(f);
  u += 0x7fffu + ((u >> 16) & 1u);   // round-to-nearest-even
  return (unsigned short)(u >> 16);
}

// ---------- generic block-sum + scan kernels (for phist) ----------
__global__ __launch_bounds__(1024) void k_bsum(const int* __restrict__ counts,
    int* __restrict__ bsums, int N) {
  __shared__ int wsum[16];
  int tid = threadIdx.x;
  int base = blockIdx.x * 4096 + tid * 4;
  int4 c = make_int4(0, 0, 0, 0);
  if (base + 3 < N) c = *(const int4*)&counts[base];
  else {
    if (base + 0 < N) c.x = counts[base + 0];
    if (base + 1 < N) c.y = counts[base + 1];
    if (base + 2 < N) c.z = counts[base + 2];
  }
  int s = c.x + c.y + c.z + c.w;
#pragma unroll
  for (int ofs = 32; ofs > 0; ofs >>= 1) s += __shfl_down(s, ofs, 64);
  if ((tid & 63) == 0) wsum[tid >> 6] = s;
  __syncthreads();
  if (tid == 0) {
    int t = 0;
#pragma unroll
    for (int i = 0; i < 16; i++) t += wsum[i];
    bsums[blockIdx.x] = t;
  }
}

__global__ __launch_bounds__(1024) void k_boff(const int* __restrict__ bsums,
    int* __restrict__ boffs, int G) {
  __shared__ int sh[1024];
  int tid = threadIdx.x;
  int v = (tid < G) ? bsums[tid] : 0;
  sh[tid] = v;
  __syncthreads();
  for (int ofs = 1; ofs < 1024; ofs <<= 1) {
    int u = (tid >= ofs) ? sh[tid - ofs] : 0;
    __syncthreads();
    sh[tid] += u;
    __syncthreads();
  }
  if (tid < G) boffs[tid] = sh[tid] - v;
  if (tid == G) boffs[G] = (G > 0) ? sh[G - 1] : 0;
}

// generic exclusive-scan tile kernel (offsets only)
__global__ __launch_bounds__(1024) void k_scan3(const int* __restrict__ counts,
    const int* __restrict__ boffs, int* __restrict__ offs, int M) {
  __shared__ int wsum[16];
  int tid = threadIdx.x;
  int lane = tid & 63, wave = tid >> 6;
  int base = blockIdx.x * 4096 + tid * 4;
  int4 c = make_int4(0, 0, 0, 0);
  if (base + 3 < M) c = *(const int4*)&counts[base];
  else {
    if (base + 0 < M) c.x = counts[base + 0];
    if (base + 1 < M) c.y = counts[base + 1];
    if (base + 2 < M) c.z = counts[base + 2];
  }
  int tsum = c.x + c.y + c.z + c.w;
  int v = tsum;
#pragma unroll
  for (int ofs = 1; ofs < 64; ofs <<= 1) {
    int u = __shfl_up(v, ofs, 64);
    if (lane >= ofs) v += u;
  }
  if (lane == 63) wsum[wave] = v;
  __syncthreads();
  if (wave == 0) {
    int w = (lane < 16) ? wsum[lane] : 0;
#pragma unroll
    for (int ofs = 1; ofs < 16; ofs <<= 1) {
      int u = __shfl_up(w, ofs, 64);
      if (lane >= ofs) w += u;
    }
    if (lane < 16) wsum[lane] = w;
  }
  __syncthreads();
  int waveoff = (wave == 0) ? 0 : wsum[wave - 1];
  int excl = boffs[blockIdx.x] + waveoff + (v - tsum);
  int r[4]; r[0] = excl; r[1] = r[0] + c.x; r[2] = r[1] + c.y; r[3] = r[2] + c.z;
#pragma unroll
  for (int k = 0; k < 4; k++) {
    int idx = base + k;
    if (idx < M) offs[idx] = r[k];
  }
}

// pass A: per-block LDS histogram over buckets -> phist[bucket*NBLK + blk]
__global__ __launch_bounds__(1024) void k_phist(const int* __restrict__ dst,
    int* __restrict__ phist, int E, int NB) {
  __shared__ int hist[1024];
  int t = blockIdx.x, tid = threadIdx.x;
  for (int i = tid; i < NB; i += 1024) hist[i] = 0;
  __syncthreads();
  int tile = (E + NBLK - 1) / NBLK;
  int lo = t * tile;
  int hi = lo + tile; if (hi > E) hi = E;
  for (int i = lo + tid; i < hi; i += 1024) atomicAdd(&hist[dst[i] >> BSH], 1);
  __syncthreads();
  for (int i = tid; i < NB; i += 1024) phist[i * NBLK + t] = hist[i];
}

// pass B: exact-offset scatter, LDS cursors, zero global atomics.
__global__ __launch_bounds__(1024) void k_pscatter(const int* __restrict__ src,
    const int* __restrict__ dst, const int* __restrict__ poff,
    unsigned* __restrict__ tmp, int E, int NB) {
  __shared__ int cur[1024];
  int t = blockIdx.x, tid = threadIdx.x;
  for (int i = tid; i < NB; i += 1024) cur[i] = poff[i * NBLK + t];
  __syncthreads();
  int tile = (E + NBLK - 1) / NBLK;
  int lo = t * tile;
  int hi = lo + tile; if (hi > E) hi = E;
  for (int i = lo + tid; i < hi; i += 1024) {
    int d = dst[i];
    int p = atomicAdd(&cur[d >> BSH], 1);
    tmp[p] = (unsigned)src[i] | ((unsigned)(d & 127) << 20);
  }
}

// pass C: per-bucket LDS histogram + scan + counting sort.
__global__ __launch_bounds__(256) void k_csort2(const unsigned* __restrict__ tmp,
    const int* __restrict__ poff, int* __restrict__ rowptr, float* __restrict__ dinv,
    int* __restrict__ col, int N, int NB, int E) {
  __shared__ int hist[128];
  __shared__ int sc[128];
  __shared__ int lcur[128];
  __shared__ unsigned buf[BCAP];
  int b = blockIdx.x;
  int n0 = b << BSH;
  int base = poff[(size_t)b * NBLK];
  int nxt = (b + 1 < NB) ? poff[(size_t)(b + 1) * NBLK] : E;
  int cnt = nxt - base;
  int tid = threadIdx.x;
  if (tid < 128) hist[tid] = 0;
  __syncthreads();
  for (int i = tid; i < cnt; i += 256) atomicAdd(&hist[(tmp[base + i] >> 20) & 127], 1);
  __syncthreads();
  if (tid < 128) sc[tid] = hist[tid];
  __syncthreads();
  for (int ofs = 1; ofs < 128; ofs <<= 1) {
    int v = (tid < 128 && tid >= ofs) ? sc[tid - ofs] : 0;
    __syncthreads();
    if (tid < 128) sc[tid] += v;
    __syncthreads();
  }
  if (tid < 128) {
    int excl = sc[tid] - hist[tid];
    lcur[tid] = excl;
    int node = n0 + tid;
    if (node < N) {
      rowptr[node] = base + excl;
      dinv[node] = rsqrtf((float)hist[tid] + 1.0f);
    }
  }
  if (b == 0 && tid == 0) rowptr[N] = E;
  __syncthreads();
  if (cnt <= BCAP) {
    for (int i = tid; i < cnt; i += 256) {
      unsigned pk = tmp[base + i];
      int p = atomicAdd(&lcur[(pk >> 20) & 127], 1);
      buf[p] = pk & 0xFFFFFu;
    }
    __syncthreads();
    for (int i = tid; i < cnt; i += 256) col[base + i] = (int)buf[i];
  } else {
    for (int i = tid; i < cnt; i += 256) {
      unsigned pk = tmp[base + i];
      int p = atomicAdd(&lcur[(pk >> 20) & 127], 1);
      col[base + p] = (int)(pk & 0xFFFFFu);
    }
  }
}

// ---------- MFMA GEMM: [M x 128] @ [128 x 128], bf16 MFMA, fp32 acc, bf16 out ----
#define WSTRIDE 136
template <int BF16IN>
__global__ __launch_bounds__(256) void k_gemm(const void* __restrict__ Ap,
    const float* __restrict__ W, bf16_t* __restrict__ Co, int M) {
  __shared__ bf16_t Wt[128 * WSTRIDE];
  int tid = threadIdx.x;
  for (int i = tid; i < 4096; i += 256) {
    int k = i >> 5;
    int nq = (i & 31) << 2;
    float4 w = *(const float4*)&W[k * CDIM + nq];
    Wt[(nq + 0) * WSTRIDE + k] = f2bf(w.x);
    Wt[(nq + 1) * WSTRIDE + k] = f2bf(w.y);
    Wt[(nq + 2) * WSTRIDE + k] = f2bf(w.z);
    Wt[(nq + 3) * WSTRIDE + k] = f2bf(w.w);
  }
  __syncthreads();

  int wave = tid >> 6;
  int lane = tid & 63;
  int m = lane & 15;
  int q = lane >> 4;
  int nstrips = (M + 63) >> 6;

  for (int s = blockIdx.x; s < nstrips; s += gridDim.x) {
    int rowA = s * 64 + wave * 16 + m;
    if (rowA > M - 1) rowA = M - 1;
    bf16x8 a[4];
#pragma unroll
    for (int c = 0; c < 4; c++) {
      if (BF16IN) {
        a[c] = *(const bf16x8*)((const bf16_t*)Ap + (size_t)rowA * CDIM + c * 32 + q * 8);
      } else {
        const float* ap = (const float*)Ap + (size_t)rowA * CDIM + c * 32 + q * 8;
        float4 f0 = *(const float4*)ap;
        float4 f1 = *(const float4*)(ap + 4);
        union { bf16x8 v; unsigned short u[8]; } ua;
        ua.u[0] = f2bf(f0.x); ua.u[1] = f2bf(f0.y); ua.u[2] = f2bf(f0.z); ua.u[3] = f2bf(f0.w);
        ua.u[4] = f2bf(f1.x); ua.u[5] = f2bf(f1.y); ua.u[6] = f2bf(f1.z); ua.u[7] = f2bf(f1.w);
        a[c] = ua.v;
      }
    }
#pragma unroll
    for (int t = 0; t < 8; t++) {
      f32x4 acc = {0.f, 0.f, 0.f, 0.f};
#pragma unroll
      for (int c = 0; c < 4; c++) {
        bf16x8 bv = *(const bf16x8*)&Wt[(t * 16 + m) * WSTRIDE + c * 32 + q * 8];
        acc = __builtin_amdgcn_mfma_f32_16x16x32_bf16(a[c], bv, acc, 0, 0, 0);
      }
#pragma unroll
      for (int r = 0; r < 4; r++) {
        int row = s * 64 + wave * 16 + q * 4 + r;
        if (row < M) Co[(size_t)row * CDIM + t * 16 + m] = f2bf(acc[r]);
      }
    }
  }
}

// ---------- per-node gather aggregation + bias + relu ----------
// One wave per node; lanes 0-31 serve even edges, 32-63 odd edges; each lane
// loads uint2 (4 channels) -> 512 B payload per gather instruction (2 rows).
// 64-edge register preload + shfl broadcast, 8 edges in flight.
__global__ __launch_bounds__(256) void k_agg(const bf16_t* __restrict__ t,
    const int* __restrict__ rowptr, const int* __restrict__ col,
    const float* __restrict__ dinv, const float* __restrict__ bias,
    bf16_t* __restrict__ out, int N) {
  int wave = threadIdx.x >> 6;
  int lane = threadIdx.x & 63;
  int node = blockIdx.x * 4 + wave;
  if (node >= N) return;
  int half = lane >> 5;          // which edge of the pair
  int c = lane & 31;             // channel quad: channels 4c..4c+3
  const uint2* tp = (const uint2*)t;   // one row = 32 uint2
  float di = dinv[node];
  uint2 sv = tp[(size_t)node * 32 + c];
  float sw = (half == 0) ? di : 0.f;   // self term counted once
  float a0 = bflo(sv.x) * sw, a1 = bfhi(sv.x) * sw;
  float a2 = bflo(sv.y) * sw, a3 = bfhi(sv.y) * sw;
  int beg = rowptr[node], end = rowptr[node + 1];
  for (int base = beg; base < end; base += 64) {
    int rem = end - base;
    int cnt = rem < 64 ? rem : 64;
    int sL = 0; float wL = 0.f;
    if (lane < cnt) { sL = col[base + lane]; wL = dinv[sL]; }
    for (int k = 0; k < cnt; k += 8) {
      int j0 = k + half, j1 = k + 2 + half, j2 = k + 4 + half, j3 = k + 6 + half;
      int s0 = __shfl(sL, j0, 64); float w0 = __shfl(wL, j0, 64);
      int s1 = __shfl(sL, j1, 64); float w1 = __shfl(wL, j1, 64);
      int s2 = __shfl(sL, j2, 64); float w2 = __shfl(wL, j2, 64);
      int s3 = __shfl(sL, j3, 64); float w3 = __shfl(wL, j3, 64);
      if (j0 >= cnt) { s0 = node; w0 = 0.f; }
      if (j1 >= cnt) { s1 = node; w1 = 0.f; }
      if (j2 >= cnt) { s2 = node; w2 = 0.f; }
      if (j3 >= cnt) { s3 = node; w3 = 0.f; }
      uint2 v0 = tp[(size_t)s0 * 32 + c];
      uint2 v1 = tp[(size_t)s1 * 32 + c];
      uint2 v2 = tp[(size_t)s2 * 32 + c];
      uint2 v3 = tp[(size_t)s3 * 32 + c];
      a0 = fmaf(bflo(v0.x), w0, a0); a1 = fmaf(bfhi(v0.x), w0, a1);
      a2 = fmaf(bflo(v0.y), w0, a2); a3 = fmaf(bfhi(v0.y), w0, a3);
      a0 = fmaf(bflo(v1.x), w1, a0); a1 = fmaf(bfhi(v1.x), w1, a1);
      a2 = fmaf(bflo(v1.y), w1, a2); a3 = fmaf(bfhi(v1.y), w1, a3);
      a0 = fmaf(bflo(v2.x), w2, a0); a1 = fmaf(bfhi(v2.x), w2, a1);
      a2 = fmaf(bflo(v2.y), w2, a2); a3 = fmaf(bfhi(v2.y), w2, a3);
      a0 = fmaf(bflo(v3.x), w3, a0); a1 = fmaf(bfhi(v3.x), w3, a1);
      a2 = fmaf(bflo(v3.y), w3, a2); a3 = fmaf(bfhi(v3.y), w3, a3);
    }
  }
  a0 += __shfl_xor(a0, 32, 64);
  a1 += __shfl_xor(a1, 32, 64);
  a2 += __shfl_xor(a2, 32, 64);
  a3 += __shfl_xor(a3, 32, 64);
  if (half == 0) {
    float4 bb = ((const float4*)bias)[c];
    float o0 = fmaxf(fmaf(di, a0, bb.x), 0.f);
    float o1 = fmaxf(fmaf(di, a1, bb.y), 0.f);
    float o2 = fmaxf(fmaf(di, a2, bb.z), 0.f);
    float o3 = fmaxf(fmaf(di, a3, bb.w), 0.f);
    uint2 o;
    o.x = ((unsigned)f2bf(o1) << 16) | f2bf(o0);
    o.y = ((unsigned)f2bf(o3) << 16) | f2bf(o2);
    ((uint2*)(out + (size_t)node * CDIM))[c] = o;
  }
}

// ---------- global mean pool: node-parallel partial sums + atomics ----------
__global__ __launch_bounds__(256) void k_pool2(const bf16_t* __restrict__ h,
    const int* __restrict__ batch, float* __restrict__ gsum, int N) {
  int tid = threadIdx.x;
  int wave = tid >> 6, lane = tid & 63;
  int i0 = blockIdx.x * PCHUNK;
  int i1 = i0 + PCHUNK; if (i1 > N) i1 = N;
  float ax = 0.f, ay = 0.f;
  int curb = -1;
  for (int i = i0 + wave; i < i1; i += 4) {
    int b = batch[i];                 // wave-uniform broadcast load
    if (b != curb) {
      if (curb >= 0) {
        atomicAdd(&gsum[curb * CDIM + lane * 2], ax);
        atomicAdd(&gsum[curb * CDIM + lane * 2 + 1], ay);
      }
      curb = b; ax = 0.f; ay = 0.f;
    }
    unsigned u = ((const unsigned*)(h + (size_t)i * CDIM))[lane];
    ax += bflo(u); ay += bfhi(u);
  }
  if (curb >= 0) {
    atomicAdd(&gsum[curb * CDIM + lane * 2], ax);
    atomicAdd(&gsum[curb * CDIM + lane * 2 + 1], ay);
  }
}

// ---------- MLP head (mlp1 also divides the pooled sum by the node count) ----
__global__ __launch_bounds__(512) void k_mlp1(const float* __restrict__ g,
    const int* __restrict__ batch, int N,
    const float* __restrict__ W, const float* __restrict__ b, float* __restrict__ o) {
  __shared__ float gs[CDIM];
  int bi = blockIdx.x, tid = threadIdx.x;
  if (tid < CDIM) {
    int lo = 0, hi = N;
    while (lo < hi) { int mid = (lo + hi) >> 1; if (batch[mid] < bi) lo = mid + 1; else hi = mid; }
    int s = lo;
    lo = 0; hi = N;
    int key = bi + 1;
    while (lo < hi) { int mid = (lo + hi) >> 1; if (batch[mid] < key) lo = mid + 1; else hi = mid; }
    float inv = 1.f / fmaxf((float)(lo - s), 1.f);
    gs[tid] = g[bi * CDIM + tid] * inv;
  }
  __syncthreads();
  if (tid < 500) {
    float acc = b[tid];
#pragma unroll 4
    for (int k = 0; k < CDIM; k++) acc = fmaf(gs[k], W[k * 500 + tid], acc);
    o[bi * 500 + tid] = fmaxf(acc, 0.f);
  }
}

__global__ __launch_bounds__(128) void k_mlp2(const float* __restrict__ a,
    const float* __restrict__ W, const float* __restrict__ b, float* __restrict__ o) {
  __shared__ float as[500];
  int bi = blockIdx.x, tid = threadIdx.x;
  for (int k = tid; k < 500; k += 128) as[k] = a[bi * 500 + k];
  __syncthreads();
  if (tid < 100) {
    float acc = b[tid];
    for (int k = 0; k < 500; k++) acc = fmaf(as[k], W[k * 100 + tid], acc);
    o[bi * 100 + tid] = fmaxf(acc, 0.f);
  }
}

__global__ __launch_bounds__(64) void k_mlp3(const float* __restrict__ a,
    const float* __restrict__ w, const float* __restrict__ b, float* __restrict__ o) {
  int bi = blockIdx.x, lane = threadIdx.x;
  float v = a[bi * 100 + lane] * w[lane];
  if (lane + 64 < 100) v = fmaf(a[bi * 100 + lane + 64], w[lane + 64], v);
#pragma unroll
  for (int ofs = 32; ofs > 0; ofs >>= 1) v += __shfl_down(v, ofs, 64);
  if (lane == 0) o[bi] = v + b[0];
}

static inline size_t align_up(size_t v) { return (v + 255) & ~(size_t)255; }

extern "C" void kernel_launch(void* const* d_in, const int* in_sizes, int n_in,
                              void* d_out, int out_size, void* d_ws, size_t ws_size,
                              hipStream_t stream) {
  const float* x   = (const float*)d_in[0];
  const int*   ei  = (const int*)d_in[1];
  const int*   bat = (const int*)d_in[2];
  const float* W1  = (const float*)d_in[3];
  const float* b1  = (const float*)d_in[4];
  const float* W2  = (const float*)d_in[5];
  const float* b2  = (const float*)d_in[6];
  const float* Wm1 = (const float*)d_in[7];
  const float* bm1 = (const float*)d_in[8];
  const float* Wm2 = (const float*)d_in[9];
  const float* bm2 = (const float*)d_in[10];
  const float* Wm3 = (const float*)d_in[11];
  const float* bm3 = (const float*)d_in[12];
  float* out = (float*)d_out;

  const int E = in_sizes[1] / 2;
  const int N = in_sizes[2];
  const int* src = ei;
  const int* dst = ei + E;
  const int NB = (N + 127) >> BSH;
  const int M  = NB * NBLK;              // phist elements
  const int G2 = (M + 4095) / 4096;

  char* p = (char*)d_ws;
  bf16_t* t    = (bf16_t*)p;   p += align_up((size_t)N * CDIM * 2);
  bf16_t* h    = (bf16_t*)p;   p += align_up((size_t)N * CDIM * 2);
  int* rowptr  = (int*)p;      p += align_up((size_t)(N + 1) * 4);
  int* colx    = (int*)p;      p += align_up((size_t)E * 4);
  unsigned* tmp= (unsigned*)p; p += align_up((size_t)E * 4);
  float* dinv  = (float*)p;    p += align_up((size_t)N * 4);
  int* phist   = (int*)p;      p += align_up((size_t)M * 4);
  int* poff    = (int*)p;      p += align_up((size_t)M * 4);
  int* bsumsB  = (int*)p;      p += align_up((size_t)G2 * 4);
  int* boffsB  = (int*)p;      p += align_up((size_t)(G2 + 1) * 4);
  float* gb    = (float*)p;    p += align_up((size_t)NGRAPH * CDIM * 4);
  float* m1    = (float*)p;    p += align_up((size_t)NGRAPH * 500 * 4);
  float* m2    = (float*)p;    p += align_up((size_t)NGRAPH * 100 * 4);
  (void)ws_size; (void)n_in; (void)out_size;

  hipMemsetAsync(gb, 0, (size_t)NGRAPH * CDIM * 4, stream);

  k_phist<<<NBLK, 1024, 0, stream>>>(dst, phist, E, NB);
  k_bsum<<<G2, 1024, 0, stream>>>(phist, bsumsB, M);
  k_boff<<<1, 1024, 0, stream>>>(bsumsB, boffsB, G2);
  k_scan3<<<G2, 1024, 0, stream>>>(phist, boffsB, poff, M);
  k_pscatter<<<NBLK, 1024, 0, stream>>>(src, dst, poff, tmp, E, NB);
  k_csort2<<<NB, 256, 0, stream>>>(tmp, poff, rowptr, dinv, colx, N, NB, E);

  int nstrips = (N + 63) >> 6;
  int gblocks = nstrips < 1024 ? nstrips : 1024;
  k_gemm<0><<<gblocks, 256, 0, stream>>>(x, W1, t, N);
  k_agg<<<(N + 3) / 4, 256, 0, stream>>>(t, rowptr, colx, dinv, b1, h, N);
  k_gemm<1><<<gblocks, 256, 0, stream>>>(h, W2, t, N);
  k_agg<<<(N + 3) / 4, 256, 0, stream>>>(t, rowptr, colx, dinv, b2, h, N);

  k_pool2<<<(N + PCHUNK - 1) / PCHUNK, 256, 0, stream>>>(h, bat, gb, N);
  k_mlp1<<<NGRAPH, 512, 0, stream>>>(gb, bat, N, Wm1, bm1, m1);
  k_mlp2<<<NGRAPH, 128, 0, stream>>>(m1, Wm2, bm2, m2);
  k_mlp3<<<NGRAPH, 64, 0, stream>>>(m2, Wm3, bm3, out);
}

// Round 10
// 378.650 us; speedup vs baseline: 2.1747x; 1.0843x over previous
//
#include <hip/hip_runtime.h>

#define CDIM 128
#define NGRAPH 256
#define BSH 7                 // 128 nodes per bucket
#define BCAP 4096             // LDS sort capacity (mean 2048, +45 sigma)
#define NBLK 256              // blocks for two-pass scatter
#define PCHUNK 512            // nodes per pooling block

typedef unsigned short bf16_t;
typedef __attribute__((ext_vector_type(8))) short bf16x8;  // MFMA A/B frag (4 VGPRs)
typedef __attribute__((ext_vector_type(4))) float f32x4;   // MFMA C/D frag

__device__ __forceinline__ float bflo(unsigned u) { return __uint_as_float(u << 16); }
__device__ __forceinline__ float bfhi(unsigned u) { return __uint_as_float(u & 0xffff0000u); }
__device__ __forceinline__ unsigned short f2bf(float f) {
  unsigned u = __float_as_uint(f);
  u += 0x7fffu + ((u >> 16) & 1u);   // round-to-nearest-even
  return (unsigned short)(u >> 16);
}

// ---------- W prep: fp32 [k][n] -> bf16 transposed [n][k], both layers ----------
__global__ __launch_bounds__(256) void k_wprep(const float* __restrict__ W1,
    const float* __restrict__ W2, bf16_t* __restrict__ Wtg1, bf16_t* __restrict__ Wtg2) {
  int i = blockIdx.x * 256 + threadIdx.x;   // 0..16383
  int n = i >> 7, k = i & 127;
  Wtg1[n * 128 + k] = f2bf(W1[k * 128 + n]);
  Wtg2[n * 128 + k] = f2bf(W2[k * 128 + n]);
}

// pass A: per-block LDS histogram over buckets -> phist[bucket*NBLK + blk]
__global__ __launch_bounds__(1024) void k_phist(const int* __restrict__ dst,
    int* __restrict__ phist, int E, int NB) {
  __shared__ int hist[1024];
  int t = blockIdx.x, tid = threadIdx.x;
  for (int i = tid; i < NB; i += 1024) hist[i] = 0;
  __syncthreads();
  int tile = (E + NBLK - 1) / NBLK;
  int lo = t * tile;
  int hi = lo + tile; if (hi > E) hi = E;
  for (int i = lo + tid; i < hi; i += 1024) atomicAdd(&hist[dst[i] >> BSH], 1);
  __syncthreads();
  for (int i = tid; i < NB; i += 1024) phist[i * NBLK + t] = hist[i];
}

// per-bucket scan: block b scans phist[b*NBLK .. +256] in place (exclusive),
// writes bucket total to btot[b].
__global__ __launch_bounds__(256) void k_bscan(int* __restrict__ phist,
    int* __restrict__ btot) {
  __shared__ int wsum[4];
  int b = blockIdx.x;
  int tid = threadIdx.x, lane = tid & 63, wave = tid >> 6;
  int orig = phist[b * NBLK + tid];
  int v = orig;
#pragma unroll
  for (int ofs = 1; ofs < 64; ofs <<= 1) {
    int u = __shfl_up(v, ofs, 64);
    if (lane >= ofs) v += u;
  }
  if (lane == 63) wsum[wave] = v;
  __syncthreads();
  int add = 0;
#pragma unroll
  for (int w = 0; w < 3; w++) if (w < wave) add += wsum[w];
  int incl = v + add;
  phist[b * NBLK + tid] = incl - orig;   // within-bucket exclusive offset
  if (tid == 255) btot[b] = incl;
}

// single-block exclusive scan of bucket totals -> bbase (bbase[NB] = E)
__global__ __launch_bounds__(1024) void k_boff(const int* __restrict__ bsums,
    int* __restrict__ boffs, int G) {
  __shared__ int sh[1024];
  int tid = threadIdx.x;
  int v = (tid < G) ? bsums[tid] : 0;
  sh[tid] = v;
  __syncthreads();
  for (int ofs = 1; ofs < 1024; ofs <<= 1) {
    int u = (tid >= ofs) ? sh[tid - ofs] : 0;
    __syncthreads();
    sh[tid] += u;
    __syncthreads();
  }
  if (tid < G) boffs[tid] = sh[tid] - v;
  if (tid == G) boffs[G] = (G > 0) ? sh[G - 1] : 0;
}

// pass B: exact-offset scatter, LDS cursors, zero global atomics.
__global__ __launch_bounds__(1024) void k_pscatter(const int* __restrict__ src,
    const int* __restrict__ dst, const int* __restrict__ phist,
    const int* __restrict__ bbase, unsigned* __restrict__ tmp, int E, int NB) {
  __shared__ int cur[1024];
  int t = blockIdx.x, tid = threadIdx.x;
  for (int i = tid; i < NB; i += 1024) cur[i] = bbase[i] + phist[i * NBLK + t];
  __syncthreads();
  int tile = (E + NBLK - 1) / NBLK;
  int lo = t * tile;
  int hi = lo + tile; if (hi > E) hi = E;
  for (int i = lo + tid; i < hi; i += 1024) {
    int d = dst[i];
    int p = atomicAdd(&cur[d >> BSH], 1);
    tmp[p] = (unsigned)src[i] | ((unsigned)(d & 127) << 20);
  }
}

// pass C: per-bucket LDS histogram + scan + counting sort; emits rowptr/dinv/col.
__global__ __launch_bounds__(256) void k_csort2(const unsigned* __restrict__ tmp,
    const int* __restrict__ bbase, int* __restrict__ rowptr, float* __restrict__ dinv,
    int* __restrict__ col, int N, int NB, int E) {
  __shared__ int hist[128];
  __shared__ int sc[128];
  __shared__ int lcur[128];
  __shared__ unsigned buf[BCAP];
  int b = blockIdx.x;
  int n0 = b << BSH;
  int base = bbase[b];
  int cnt = bbase[b + 1] - base;
  int tid = threadIdx.x;
  if (tid < 128) hist[tid] = 0;
  __syncthreads();
  for (int i = tid; i < cnt; i += 256) atomicAdd(&hist[(tmp[base + i] >> 20) & 127], 1);
  __syncthreads();
  if (tid < 128) sc[tid] = hist[tid];
  __syncthreads();
  for (int ofs = 1; ofs < 128; ofs <<= 1) {
    int v = (tid < 128 && tid >= ofs) ? sc[tid - ofs] : 0;
    __syncthreads();
    if (tid < 128) sc[tid] += v;
    __syncthreads();
  }
  if (tid < 128) {
    int excl = sc[tid] - hist[tid];
    lcur[tid] = excl;
    int node = n0 + tid;
    if (node < N) {
      rowptr[node] = base + excl;
      dinv[node] = rsqrtf((float)hist[tid] + 1.0f);
    }
  }
  if (b == 0 && tid == 0) rowptr[N] = E;
  __syncthreads();
  if (cnt <= BCAP) {
    for (int i = tid; i < cnt; i += 256) {
      unsigned pk = tmp[base + i];
      int p = atomicAdd(&lcur[(pk >> 20) & 127], 1);
      buf[p] = pk & 0xFFFFFu;
    }
    __syncthreads();
    for (int i = tid; i < cnt; i += 256) col[base + i] = (int)buf[i];
  } else {
    for (int i = tid; i < cnt; i += 256) {
      unsigned pk = tmp[base + i];
      int p = atomicAdd(&lcur[(pk >> 20) & 127], 1);
      col[base + p] = (int)(pk & 0xFFFFFu);
    }
  }
}

// ---------- MFMA GEMM: [M x 128] @ [128 x 128], bf16 MFMA, fp32 acc, bf16 out ----
// Wtg is pre-transposed bf16 [n][k]; staged to LDS via raw uint4 copies.
#define WSTRIDE 136
template <int BF16IN>
__global__ __launch_bounds__(256) void k_gemm(const void* __restrict__ Ap,
    const bf16_t* __restrict__ Wtg, bf16_t* __restrict__ Co, int M) {
  __shared__ bf16_t Wt[128 * WSTRIDE];
  int tid = threadIdx.x;
  for (int c2 = tid; c2 < 2048; c2 += 256) {   // 2048 x 8-bf16 chunks
    int n = c2 >> 4;
    int k8 = (c2 & 15) << 3;
    *(uint4*)&Wt[n * WSTRIDE + k8] = *(const uint4*)&Wtg[n * 128 + k8];
  }
  __syncthreads();

  int wave = tid >> 6;
  int lane = tid & 63;
  int m = lane & 15;
  int q = lane >> 4;
  int nstrips = (M + 63) >> 6;

  for (int s = blockIdx.x; s < nstrips; s += gridDim.x) {
    int rowA = s * 64 + wave * 16 + m;
    if (rowA > M - 1) rowA = M - 1;
    bf16x8 a[4];
#pragma unroll
    for (int c = 0; c < 4; c++) {
      if (BF16IN) {
        a[c] = *(const bf16x8*)((const bf16_t*)Ap + (size_t)rowA * CDIM + c * 32 + q * 8);
      } else {
        const float* ap = (const float*)Ap + (size_t)rowA * CDIM + c * 32 + q * 8;
        float4 f0 = *(const float4*)ap;
        float4 f1 = *(const float4*)(ap + 4);
        union { bf16x8 v; unsigned short u[8]; } ua;
        ua.u[0] = f2bf(f0.x); ua.u[1] = f2bf(f0.y); ua.u[2] = f2bf(f0.z); ua.u[3] = f2bf(f0.w);
        ua.u[4] = f2bf(f1.x); ua.u[5] = f2bf(f1.y); ua.u[6] = f2bf(f1.z); ua.u[7] = f2bf(f1.w);
        a[c] = ua.v;
      }
    }
#pragma unroll
    for (int t = 0; t < 8; t++) {
      f32x4 acc = {0.f, 0.f, 0.f, 0.f};
#pragma unroll
      for (int c = 0; c < 4; c++) {
        bf16x8 bv = *(const bf16x8*)&Wt[(t * 16 + m) * WSTRIDE + c * 32 + q * 8];
        acc = __builtin_amdgcn_mfma_f32_16x16x32_bf16(a[c], bv, acc, 0, 0, 0);
      }
#pragma unroll
      for (int r = 0; r < 4; r++) {
        int row = s * 64 + wave * 16 + q * 4 + r;
        if (row < M) Co[(size_t)row * CDIM + t * 16 + m] = f2bf(acc[r]);
      }
    }
  }
}

// ---------- per-node gather aggregation + bias + relu ----------
// One wave per node; lanes 0-31 serve even edges, 32-63 odd edges; each lane
// loads uint2 (4 channels) -> 512 B payload per gather instruction (2 rows).
__global__ __launch_bounds__(256) void k_agg(const bf16_t* __restrict__ t,
    const int* __restrict__ rowptr, const int* __restrict__ col,
    const float* __restrict__ dinv, const float* __restrict__ bias,
    bf16_t* __restrict__ out, int N) {
  int wave = threadIdx.x >> 6;
  int lane = threadIdx.x & 63;
  int node = blockIdx.x * 4 + wave;
  if (node >= N) return;
  int half = lane >> 5;
  int c = lane & 31;
  const uint2* tp = (const uint2*)t;
  float di = dinv[node];
  uint2 sv = tp[(size_t)node * 32 + c];
  float sw = (half == 0) ? di : 0.f;
  float a0 = bflo(sv.x) * sw, a1 = bfhi(sv.x) * sw;
  float a2 = bflo(sv.y) * sw, a3 = bfhi(sv.y) * sw;
  int beg = rowptr[node], end = rowptr[node + 1];
  for (int base = beg; base < end; base += 64) {
    int rem = end - base;
    int cnt = rem < 64 ? rem : 64;
    int sL = 0; float wL = 0.f;
    if (lane < cnt) { sL = col[base + lane]; wL = dinv[sL]; }
    for (int k = 0; k < cnt; k += 8) {
      int j0 = k + half, j1 = k + 2 + half, j2 = k + 4 + half, j3 = k + 6 + half;
      int s0 = __shfl(sL, j0, 64); float w0 = __shfl(wL, j0, 64);
      int s1 = __shfl(sL, j1, 64); float w1 = __shfl(wL, j1, 64);
      int s2 = __shfl(sL, j2, 64); float w2 = __shfl(wL, j2, 64);
      int s3 = __shfl(sL, j3, 64); float w3 = __shfl(wL, j3, 64);
      if (j0 >= cnt) { s0 = node; w0 = 0.f; }
      if (j1 >= cnt) { s1 = node; w1 = 0.f; }
      if (j2 >= cnt) { s2 = node; w2 = 0.f; }
      if (j3 >= cnt) { s3 = node; w3 = 0.f; }
      uint2 v0 = tp[(size_t)s0 * 32 + c];
      uint2 v1 = tp[(size_t)s1 * 32 + c];
      uint2 v2 = tp[(size_t)s2 * 32 + c];
      uint2 v3 = tp[(size_t)s3 * 32 + c];
      a0 = fmaf(bflo(v0.x), w0, a0); a1 = fmaf(bfhi(v0.x), w0, a1);
      a2 = fmaf(bflo(v0.y), w0, a2); a3 = fmaf(bfhi(v0.y), w0, a3);
      a0 = fmaf(bflo(v1.x), w1, a0); a1 = fmaf(bfhi(v1.x), w1, a1);
      a2 = fmaf(bflo(v1.y), w1, a2); a3 = fmaf(bfhi(v1.y), w1, a3);
      a0 = fmaf(bflo(v2.x), w2, a0); a1 = fmaf(bfhi(v2.x), w2, a1);
      a2 = fmaf(bflo(v2.y), w2, a2); a3 = fmaf(bfhi(v2.y), w2, a3);
      a0 = fmaf(bflo(v3.x), w3, a0); a1 = fmaf(bfhi(v3.x), w3, a1);
      a2 = fmaf(bflo(v3.y), w3, a2); a3 = fmaf(bfhi(v3.y), w3, a3);
    }
  }
  a0 += __shfl_xor(a0, 32, 64);
  a1 += __shfl_xor(a1, 32, 64);
  a2 += __shfl_xor(a2, 32, 64);
  a3 += __shfl_xor(a3, 32, 64);
  if (half == 0) {
    float4 bb = ((const float4*)bias)[c];
    float o0 = fmaxf(fmaf(di, a0, bb.x), 0.f);
    float o1 = fmaxf(fmaf(di, a1, bb.y), 0.f);
    float o2 = fmaxf(fmaf(di, a2, bb.z), 0.f);
    float o3 = fmaxf(fmaf(di, a3, bb.w), 0.f);
    uint2 o;
    o.x = ((unsigned)f2bf(o1) << 16) | f2bf(o0);
    o.y = ((unsigned)f2bf(o3) << 16) | f2bf(o2);
    ((uint2*)(out + (size_t)node * CDIM))[c] = o;
  }
}

// ---------- global mean pool: node-parallel partial sums + atomics ----------
__global__ __launch_bounds__(256) void k_pool2(const bf16_t* __restrict__ h,
    const int* __restrict__ batch, float* __restrict__ gsum, int N) {
  int tid = threadIdx.x;
  int wave = tid >> 6, lane = tid & 63;
  int i0 = blockIdx.x * PCHUNK;
  int i1 = i0 + PCHUNK; if (i1 > N) i1 = N;
  float ax = 0.f, ay = 0.f;
  int curb = -1;
  for (int i = i0 + wave; i < i1; i += 4) {
    int b = batch[i];
    if (b != curb) {
      if (curb >= 0) {
        atomicAdd(&gsum[curb * CDIM + lane * 2], ax);
        atomicAdd(&gsum[curb * CDIM + lane * 2 + 1], ay);
      }
      curb = b; ax = 0.f; ay = 0.f;
    }
    unsigned u = ((const unsigned*)(h + (size_t)i * CDIM))[lane];
    ax += bflo(u); ay += bfhi(u);
  }
  if (curb >= 0) {
    atomicAdd(&gsum[curb * CDIM + lane * 2], ax);
    atomicAdd(&gsum[curb * CDIM + lane * 2 + 1], ay);
  }
}

// ---------- MLP head (mlp1 also divides the pooled sum by the node count) ----
__global__ __launch_bounds__(512) void k_mlp1(const float* __restrict__ g,
    const int* __restrict__ batch, int N,
    const float* __restrict__ W, const float* __restrict__ b, float* __restrict__ o) {
  __shared__ float gs[CDIM];
  int bi = blockIdx.x, tid = threadIdx.x;
  if (tid < CDIM) {
    int lo = 0, hi = N;
    while (lo < hi) { int mid = (lo + hi) >> 1; if (batch[mid] < bi) lo = mid + 1; else hi = mid; }
    int s = lo;
    lo = 0; hi = N;
    int key = bi + 1;
    while (lo < hi) { int mid = (lo + hi) >> 1; if (batch[mid] < key) lo = mid + 1; else hi = mid; }
    float inv = 1.f / fmaxf((float)(lo - s), 1.f);
    gs[tid] = g[bi * CDIM + tid] * inv;
  }
  __syncthreads();
  if (tid < 500) {
    float acc = b[tid];
#pragma unroll 4
    for (int k = 0; k < CDIM; k++) acc = fmaf(gs[k], W[k * 500 + tid], acc);
    o[bi * 500 + tid] = fmaxf(acc, 0.f);
  }
}

__global__ __launch_bounds__(128) void k_mlp2(const float* __restrict__ a,
    const float* __restrict__ W, const float* __restrict__ b, float* __restrict__ o) {
  __shared__ float as[500];
  int bi = blockIdx.x, tid = threadIdx.x;
  for (int k = tid; k < 500; k += 128) as[k] = a[bi * 500 + k];
  __syncthreads();
  if (tid < 100) {
    float acc = b[tid];
    for (int k = 0; k < 500; k++) acc = fmaf(as[k], W[k * 100 + tid], acc);
    o[bi * 100 + tid] = fmaxf(acc, 0.f);
  }
}

__global__ __launch_bounds__(64) void k_mlp3(const float* __restrict__ a,
    const float* __restrict__ w, const float* __restrict__ b, float* __restrict__ o) {
  int bi = blockIdx.x, lane = threadIdx.x;
  float v = a[bi * 100 + lane] * w[lane];
  if (lane + 64 < 100) v = fmaf(a[bi * 100 + lane + 64], w[lane + 64], v);
#pragma unroll
  for (int ofs = 32; ofs > 0; ofs >>= 1) v += __shfl_down(v, ofs, 64);
  if (lane == 0) o[bi] = v + b[0];
}

static inline size_t align_up(size_t v) { return (v + 255) & ~(size_t)255; }

extern "C" void kernel_launch(void* const* d_in, const int* in_sizes, int n_in,
                              void* d_out, int out_size, void* d_ws, size_t ws_size,
                              hipStream_t stream) {
  const float* x   = (const float*)d_in[0];
  const int*   ei  = (const int*)d_in[1];
  const int*   bat = (const int*)d_in[2];
  const float* W1  = (const float*)d_in[3];
  const float* b1  = (const float*)d_in[4];
  const float* W2  = (const float*)d_in[5];
  const float* b2  = (const float*)d_in[6];
  const float* Wm1 = (const float*)d_in[7];
  const float* bm1 = (const float*)d_in[8];
  const float* Wm2 = (const float*)d_in[9];
  const float* bm2 = (const float*)d_in[10];
  const float* Wm3 = (const float*)d_in[11];
  const float* bm3 = (const float*)d_in[12];
  float* out = (float*)d_out;

  const int E = in_sizes[1] / 2;
  const int N = in_sizes[2];
  const int* src = ei;
  const int* dst = ei + E;
  const int NB = (N + 127) >> BSH;
  const int M  = NB * NBLK;              // phist elements

  char* p = (char*)d_ws;
  bf16_t* t    = (bf16_t*)p;   p += align_up((size_t)N * CDIM * 2);
  bf16_t* h    = (bf16_t*)p;   p += align_up((size_t)N * CDIM * 2);
  int* rowptr  = (int*)p;      p += align_up((size_t)(N + 1) * 4);
  int* colx    = (int*)p;      p += align_up((size_t)E * 4);
  unsigned* tmp= (unsigned*)p; p += align_up((size_t)E * 4);
  float* dinv  = (float*)p;    p += align_up((size_t)N * 4);
  int* phist   = (int*)p;      p += align_up((size_t)M * 4);
  int* btot    = (int*)p;      p += align_up((size_t)NB * 4);
  int* bbase   = (int*)p;      p += align_up((size_t)(NB + 1) * 4);
  bf16_t* Wtg1 = (bf16_t*)p;   p += align_up((size_t)CDIM * CDIM * 2);
  bf16_t* Wtg2 = (bf16_t*)p;   p += align_up((size_t)CDIM * CDIM * 2);
  float* gb    = (float*)p;    p += align_up((size_t)NGRAPH * CDIM * 4);
  float* m1    = (float*)p;    p += align_up((size_t)NGRAPH * 500 * 4);
  float* m2    = (float*)p;    p += align_up((size_t)NGRAPH * 100 * 4);
  (void)ws_size; (void)n_in; (void)out_size;

  hipMemsetAsync(gb, 0, (size_t)NGRAPH * CDIM * 4, stream);

  k_wprep<<<64, 256, 0, stream>>>(W1, W2, Wtg1, Wtg2);
  k_phist<<<NBLK, 1024, 0, stream>>>(dst, phist, E, NB);
  k_bscan<<<NB, 256, 0, stream>>>(phist, btot);
  k_boff<<<1, 1024, 0, stream>>>(btot, bbase, NB);
  k_pscatter<<<NBLK, 1024, 0, stream>>>(src, dst, phist, bbase, tmp, E, NB);
  k_csort2<<<NB, 256, 0, stream>>>(tmp, bbase, rowptr, dinv, colx, N, NB, E);

  k_gemm<0><<<512, 256, 0, stream>>>(x, Wtg1, t, N);
  k_agg<<<(N + 3) / 4, 256, 0, stream>>>(t, rowptr, colx, dinv, b1, h, N);
  k_gemm<1><<<512, 256, 0, stream>>>(h, Wtg2, t, N);
  k_agg<<<(N + 3) / 4, 256, 0, stream>>>(t, rowptr, colx, dinv, b2, h, N);

  k_pool2<<<(N + PCHUNK - 1) / PCHUNK, 256, 0, stream>>>(h, bat, gb, N);
  k_mlp1<<<NGRAPH, 512, 0, stream>>>(gb, bat, N, Wm1, bm1, m1);
  k_mlp2<<<NGRAPH, 128, 0, stream>>>(m1, Wm2, bm2, m2);
  k_mlp3<<<NGRAPH, 64, 0, stream>>>(m2, Wm3, bm3, out);
}

// Round 11
// 360.715 us; speedup vs baseline: 2.2828x; 1.0497x over previous
//
#include <hip/hip_runtime.h>

#define CDIM 128
#define NGRAPH 256
#define BSH 7                 // 128 nodes per bucket
#define BCAP 4096             // LDS sort capacity (mean 2048, +45 sigma)
#define NBLK 256              // blocks for two-pass scatter

typedef unsigned short bf16_t;
typedef __attribute__((ext_vector_type(8))) short bf16x8;  // MFMA A/B frag (4 VGPRs)
typedef __attribute__((ext_vector_type(4))) float f32x4;   // MFMA C/D frag

__device__ __forceinline__ float bflo(unsigned u) { return __uint_as_float(u << 16); }
__device__ __forceinline__ float bfhi(unsigned u) { return __uint_as_float(u & 0xffff0000u); }
__device__ __forceinline__ unsigned short f2bf(float f) {
  unsigned u = __float_as_uint(f);
  u += 0x7fffu + ((u >> 16) & 1u);   // round-to-nearest-even
  return (unsigned short)(u >> 16);
}

// ---------- W prep: fp32 [k][n] -> bf16 transposed [n][k], both layers ----------
__global__ __launch_bounds__(256) void k_wprep(const float* __restrict__ W1,
    const float* __restrict__ W2, bf16_t* __restrict__ Wtg1, bf16_t* __restrict__ Wtg2) {
  int i = blockIdx.x * 256 + threadIdx.x;   // 0..16383
  int n = i >> 7, k = i & 127;
  Wtg1[n * 128 + k] = f2bf(W1[k * 128 + n]);
  Wtg2[n * 128 + k] = f2bf(W2[k * 128 + n]);
}

// pass A: per-block LDS histogram over buckets -> phist[bucket*NBLK + blk]
__global__ __launch_bounds__(1024) void k_phist(const int* __restrict__ dst,
    int* __restrict__ phist, int E, int NB) {
  __shared__ int hist[1024];
  int t = blockIdx.x, tid = threadIdx.x;
  for (int i = tid; i < NB; i += 1024) hist[i] = 0;
  __syncthreads();
  int tile = (E + NBLK - 1) / NBLK;
  int lo = t * tile;
  int hi = lo + tile; if (hi > E) hi = E;
  for (int i = lo + tid; i < hi; i += 1024) atomicAdd(&hist[dst[i] >> BSH], 1);
  __syncthreads();
  for (int i = tid; i < NB; i += 1024) phist[i * NBLK + t] = hist[i];
}

// per-bucket scan: block b scans phist[b*NBLK .. +256] in place (exclusive),
// writes bucket total to btot[b].
__global__ __launch_bounds__(256) void k_bscan(int* __restrict__ phist,
    int* __restrict__ btot) {
  __shared__ int wsum[4];
  int b = blockIdx.x;
  int tid = threadIdx.x, lane = tid & 63, wave = tid >> 6;
  int orig = phist[b * NBLK + tid];
  int v = orig;
#pragma unroll
  for (int ofs = 1; ofs < 64; ofs <<= 1) {
    int u = __shfl_up(v, ofs, 64);
    if (lane >= ofs) v += u;
  }
  if (lane == 63) wsum[wave] = v;
  __syncthreads();
  int add = 0;
#pragma unroll
  for (int w = 0; w < 3; w++) if (w < wave) add += wsum[w];
  int incl = v + add;
  phist[b * NBLK + tid] = incl - orig;   // within-bucket exclusive offset
  if (tid == 255) btot[b] = incl;
}

// single-block exclusive scan of bucket totals -> bbase (bbase[NB] = E)
__global__ __launch_bounds__(1024) void k_boff(const int* __restrict__ bsums,
    int* __restrict__ boffs, int G) {
  __shared__ int sh[1024];
  int tid = threadIdx.x;
  int v = (tid < G) ? bsums[tid] : 0;
  sh[tid] = v;
  __syncthreads();
  for (int ofs = 1; ofs < 1024; ofs <<= 1) {
    int u = (tid >= ofs) ? sh[tid - ofs] : 0;
    __syncthreads();
    sh[tid] += u;
    __syncthreads();
  }
  if (tid < G) boffs[tid] = sh[tid] - v;
  if (tid == G) boffs[G] = (G > 0) ? sh[G - 1] : 0;
}

// pass B: exact-offset scatter, LDS cursors, zero global atomics.
__global__ __launch_bounds__(1024) void k_pscatter(const int* __restrict__ src,
    const int* __restrict__ dst, const int* __restrict__ phist,
    const int* __restrict__ bbase, unsigned* __restrict__ tmp, int E, int NB) {
  __shared__ int cur[1024];
  int t = blockIdx.x, tid = threadIdx.x;
  for (int i = tid; i < NB; i += 1024) cur[i] = bbase[i] + phist[i * NBLK + t];
  __syncthreads();
  int tile = (E + NBLK - 1) / NBLK;
  int lo = t * tile;
  int hi = lo + tile; if (hi > E) hi = E;
  for (int i = lo + tid; i < hi; i += 1024) {
    int d = dst[i];
    int p = atomicAdd(&cur[d >> BSH], 1);
    tmp[p] = (unsigned)src[i] | ((unsigned)(d & 127) << 20);
  }
}

// pass C: per-bucket LDS histogram + scan + counting sort; emits rowptr/dinv/col.
__global__ __launch_bounds__(256) void k_csort2(const unsigned* __restrict__ tmp,
    const int* __restrict__ bbase, int* __restrict__ rowptr, float* __restrict__ dinv,
    int* __restrict__ col, int N, int NB, int E) {
  __shared__ int hist[128];
  __shared__ int sc[128];
  __shared__ int lcur[128];
  __shared__ unsigned buf[BCAP];
  int b = blockIdx.x;
  int n0 = b << BSH;
  int base = bbase[b];
  int cnt = bbase[b + 1] - base;
  int tid = threadIdx.x;
  if (tid < 128) hist[tid] = 0;
  __syncthreads();
  for (int i = tid; i < cnt; i += 256) atomicAdd(&hist[(tmp[base + i] >> 20) & 127], 1);
  __syncthreads();
  if (tid < 128) sc[tid] = hist[tid];
  __syncthreads();
  for (int ofs = 1; ofs < 128; ofs <<= 1) {
    int v = (tid < 128 && tid >= ofs) ? sc[tid - ofs] : 0;
    __syncthreads();
    if (tid < 128) sc[tid] += v;
    __syncthreads();
  }
  if (tid < 128) {
    int excl = sc[tid] - hist[tid];
    lcur[tid] = excl;
    int node = n0 + tid;
    if (node < N) {
      rowptr[node] = base + excl;
      dinv[node] = rsqrtf((float)hist[tid] + 1.0f);
    }
  }
  if (b == 0 && tid == 0) rowptr[N] = E;
  __syncthreads();
  if (cnt <= BCAP) {
    for (int i = tid; i < cnt; i += 256) {
      unsigned pk = tmp[base + i];
      int p = atomicAdd(&lcur[(pk >> 20) & 127], 1);
      buf[p] = pk & 0xFFFFFu;
    }
    __syncthreads();
    for (int i = tid; i < cnt; i += 256) col[base + i] = (int)buf[i];
  } else {
    for (int i = tid; i < cnt; i += 256) {
      unsigned pk = tmp[base + i];
      int p = atomicAdd(&lcur[(pk >> 20) & 127], 1);
      col[base + p] = (int)(pk & 0xFFFFFu);
    }
  }
}

// ---------- MFMA GEMM: [M x 128] @ [128 x 128], bf16 MFMA, fp32 acc, bf16 out ----
#define WSTRIDE 136
template <int BF16IN>
__global__ __launch_bounds__(256) void k_gemm(const void* __restrict__ Ap,
    const bf16_t* __restrict__ Wtg, bf16_t* __restrict__ Co, int M) {
  __shared__ bf16_t Wt[128 * WSTRIDE];
  int tid = threadIdx.x;
  for (int c2 = tid; c2 < 2048; c2 += 256) {   // 2048 x 8-bf16 chunks
    int n = c2 >> 4;
    int k8 = (c2 & 15) << 3;
    *(uint4*)&Wt[n * WSTRIDE + k8] = *(const uint4*)&Wtg[n * 128 + k8];
  }
  __syncthreads();

  int wave = tid >> 6;
  int lane = tid & 63;
  int m = lane & 15;
  int q = lane >> 4;
  int nstrips = (M + 63) >> 6;

  for (int s = blockIdx.x; s < nstrips; s += gridDim.x) {
    int rowA = s * 64 + wave * 16 + m;
    if (rowA > M - 1) rowA = M - 1;
    bf16x8 a[4];
#pragma unroll
    for (int c = 0; c < 4; c++) {
      if (BF16IN) {
        a[c] = *(const bf16x8*)((const bf16_t*)Ap + (size_t)rowA * CDIM + c * 32 + q * 8);
      } else {
        const float* ap = (const float*)Ap + (size_t)rowA * CDIM + c * 32 + q * 8;
        float4 f0 = *(const float4*)ap;
        float4 f1 = *(const float4*)(ap + 4);
        union { bf16x8 v; unsigned short u[8]; } ua;
        ua.u[0] = f2bf(f0.x); ua.u[1] = f2bf(f0.y); ua.u[2] = f2bf(f0.z); ua.u[3] = f2bf(f0.w);
        ua.u[4] = f2bf(f1.x); ua.u[5] = f2bf(f1.y); ua.u[6] = f2bf(f1.z); ua.u[7] = f2bf(f1.w);
        a[c] = ua.v;
      }
    }
#pragma unroll
    for (int t = 0; t < 8; t++) {
      f32x4 acc = {0.f, 0.f, 0.f, 0.f};
#pragma unroll
      for (int c = 0; c < 4; c++) {
        bf16x8 bv = *(const bf16x8*)&Wt[(t * 16 + m) * WSTRIDE + c * 32 + q * 8];
        acc = __builtin_amdgcn_mfma_f32_16x16x32_bf16(a[c], bv, acc, 0, 0, 0);
      }
#pragma unroll
      for (int r = 0; r < 4; r++) {
        int row = s * 64 + wave * 16 + q * 4 + r;
        if (row < M) Co[(size_t)row * CDIM + t * 16 + m] = f2bf(acc[r]);
      }
    }
  }
}

// ---------- gather aggregation + bias + relu; POOL=1 fuses mean-pool ----------
// One wave per node (POOL=0) or 16 consecutive nodes per wave (POOL=1).
// Lanes 0-31 even edges, 32-63 odd edges; uint2 loads (4 ch); 16 edges in flight.
template <int POOL>
__global__ __launch_bounds__(256) void k_agg(const bf16_t* __restrict__ t,
    const int* __restrict__ rowptr, const int* __restrict__ col,
    const float* __restrict__ dinv, const float* __restrict__ bias,
    bf16_t* __restrict__ out, const int* __restrict__ batch,
    float* __restrict__ gsum, int N) {
  int wave = threadIdx.x >> 6;
  int lane = threadIdx.x & 63;
  int half = lane >> 5;
  int c = lane & 31;
  const uint2* tp = (const uint2*)t;
  float4 bb = ((const float4*)bias)[c];
  int n0, nEnd;
  if (POOL) { n0 = (blockIdx.x * 4 + wave) * 16; nEnd = n0 + 16; }
  else      { n0 = blockIdx.x * 4 + wave;        nEnd = n0 + 1; }
  if (n0 >= N) return;
  if (nEnd > N) nEnd = N;
  float p0 = 0.f, p1 = 0.f, p2 = 0.f, p3 = 0.f;
  int curb = POOL ? batch[n0] : 0;

  for (int node = n0; node < nEnd; node++) {
    float di = dinv[node];
    uint2 sv = tp[(size_t)node * 32 + c];
    float sw = (half == 0) ? di : 0.f;   // self term counted once
    float a0 = bflo(sv.x) * sw, a1 = bfhi(sv.x) * sw;
    float a2 = bflo(sv.y) * sw, a3 = bfhi(sv.y) * sw;
    int beg = rowptr[node], end = rowptr[node + 1];
    for (int base = beg; base < end; base += 64) {
      int rem = end - base;
      int cnt = rem < 64 ? rem : 64;
      int sL = 0; float wL = 0.f;
      if (lane < cnt) { sL = col[base + lane]; wL = dinv[sL]; }
      for (int k = 0; k < cnt; k += 16) {
        int s[8]; float w[8];
#pragma unroll
        for (int i = 0; i < 8; i++) {
          int j = k + 2 * i + half;
          s[i] = __shfl(sL, j, 64); w[i] = __shfl(wL, j, 64);
          if (j >= cnt) { s[i] = node; w[i] = 0.f; }
        }
        uint2 v[8];
#pragma unroll
        for (int i = 0; i < 8; i++) v[i] = tp[(size_t)s[i] * 32 + c];
#pragma unroll
        for (int i = 0; i < 8; i++) {
          a0 = fmaf(bflo(v[i].x), w[i], a0); a1 = fmaf(bfhi(v[i].x), w[i], a1);
          a2 = fmaf(bflo(v[i].y), w[i], a2); a3 = fmaf(bfhi(v[i].y), w[i], a3);
        }
      }
    }
    a0 += __shfl_xor(a0, 32, 64);
    a1 += __shfl_xor(a1, 32, 64);
    a2 += __shfl_xor(a2, 32, 64);
    a3 += __shfl_xor(a3, 32, 64);
    if (half == 0) {
      float o0 = fmaxf(fmaf(di, a0, bb.x), 0.f);
      float o1 = fmaxf(fmaf(di, a1, bb.y), 0.f);
      float o2 = fmaxf(fmaf(di, a2, bb.z), 0.f);
      float o3 = fmaxf(fmaf(di, a3, bb.w), 0.f);
      if (!POOL) {
        uint2 o;
        o.x = ((unsigned)f2bf(o1) << 16) | f2bf(o0);
        o.y = ((unsigned)f2bf(o3) << 16) | f2bf(o2);
        ((uint2*)(out + (size_t)node * CDIM))[c] = o;
      } else {
        int b = batch[node];
        if (b != curb) {
          atomicAdd(&gsum[curb * CDIM + c * 4 + 0], p0);
          atomicAdd(&gsum[curb * CDIM + c * 4 + 1], p1);
          atomicAdd(&gsum[curb * CDIM + c * 4 + 2], p2);
          atomicAdd(&gsum[curb * CDIM + c * 4 + 3], p3);
          curb = b; p0 = p1 = p2 = p3 = 0.f;
        }
        // accumulate in bf16-rounded precision to match the unfused reference path
        p0 += __uint_as_float((unsigned)f2bf(o0) << 16);
        p1 += __uint_as_float((unsigned)f2bf(o1) << 16);
        p2 += __uint_as_float((unsigned)f2bf(o2) << 16);
        p3 += __uint_as_float((unsigned)f2bf(o3) << 16);
      }
    }
  }
  if (POOL && half == 0) {
    atomicAdd(&gsum[curb * CDIM + c * 4 + 0], p0);
    atomicAdd(&gsum[curb * CDIM + c * 4 + 1], p1);
    atomicAdd(&gsum[curb * CDIM + c * 4 + 2], p2);
    atomicAdd(&gsum[curb * CDIM + c * 4 + 3], p3);
  }
}

// ---------- MLP head (mlp1 also divides the pooled sum by the node count) ----
__global__ __launch_bounds__(512) void k_mlp1(const float* __restrict__ g,
    const int* __restrict__ batch, int N,
    const float* __restrict__ W, const float* __restrict__ b, float* __restrict__ o) {
  __shared__ float gs[CDIM];
  int bi = blockIdx.x, tid = threadIdx.x;
  if (tid < CDIM) {
    int lo = 0, hi = N;
    while (lo < hi) { int mid = (lo + hi) >> 1; if (batch[mid] < bi) lo = mid + 1; else hi = mid; }
    int s = lo;
    lo = 0; hi = N;
    int key = bi + 1;
    while (lo < hi) { int mid = (lo + hi) >> 1; if (batch[mid] < key) lo = mid + 1; else hi = mid; }
    float inv = 1.f / fmaxf((float)(lo - s), 1.f);
    gs[tid] = g[bi * CDIM + tid] * inv;
  }
  __syncthreads();
  if (tid < 500) {
    float acc = b[tid];
#pragma unroll 4
    for (int k = 0; k < CDIM; k++) acc = fmaf(gs[k], W[k * 500 + tid], acc);
    o[bi * 500 + tid] = fmaxf(acc, 0.f);
  }
}

// fused mlp2 (relu) + mlp3 (dot)
__global__ __launch_bounds__(128) void k_mlp23(const float* __restrict__ a,
    const float* __restrict__ W2m, const float* __restrict__ b2m,
    const float* __restrict__ w3, const float* __restrict__ b3,
    float* __restrict__ o) {
  __shared__ float as[500];
  __shared__ float m2s[100];
  int bi = blockIdx.x, tid = threadIdx.x;
  for (int k = tid; k < 500; k += 128) as[k] = a[bi * 500 + k];
  __syncthreads();
  if (tid < 100) {
    float acc = b2m[tid];
    for (int k = 0; k < 500; k++) acc = fmaf(as[k], W2m[k * 100 + tid], acc);
    m2s[tid] = fmaxf(acc, 0.f) * w3[tid];
  }
  __syncthreads();
  if (tid < 64) {
    float v = m2s[tid] + ((tid + 64 < 100) ? m2s[tid + 64] : 0.f);
#pragma unroll
    for (int ofs = 32; ofs > 0; ofs >>= 1) v += __shfl_down(v, ofs, 64);
    if (tid == 0) o[bi] = v + b3[0];
  }
}

static inline size_t align_up(size_t v) { return (v + 255) & ~(size_t)255; }

extern "C" void kernel_launch(void* const* d_in, const int* in_sizes, int n_in,
                              void* d_out, int out_size, void* d_ws, size_t ws_size,
                              hipStream_t stream) {
  const float* x   = (const float*)d_in[0];
  const int*   ei  = (const int*)d_in[1];
  const int*   bat = (const int*)d_in[2];
  const float* W1  = (const float*)d_in[3];
  const float* b1  = (const float*)d_in[4];
  const float* W2  = (const float*)d_in[5];
  const float* b2  = (const float*)d_in[6];
  const float* Wm1 = (const float*)d_in[7];
  const float* bm1 = (const float*)d_in[8];
  const float* Wm2 = (const float*)d_in[9];
  const float* bm2 = (const float*)d_in[10];
  const float* Wm3 = (const float*)d_in[11];
  const float* bm3 = (const float*)d_in[12];
  float* out = (float*)d_out;

  const int E = in_sizes[1] / 2;
  const int N = in_sizes[2];
  const int* src = ei;
  const int* dst = ei + E;
  const int NB = (N + 127) >> BSH;
  const int M  = NB * NBLK;              // phist elements

  char* p = (char*)d_ws;
  bf16_t* t    = (bf16_t*)p;   p += align_up((size_t)N * CDIM * 2);
  bf16_t* h    = (bf16_t*)p;   p += align_up((size_t)N * CDIM * 2);
  int* rowptr  = (int*)p;      p += align_up((size_t)(N + 1) * 4);
  int* colx    = (int*)p;      p += align_up((size_t)E * 4);
  unsigned* tmp= (unsigned*)p; p += align_up((size_t)E * 4);
  float* dinv  = (float*)p;    p += align_up((size_t)N * 4);
  int* phist   = (int*)p;      p += align_up((size_t)M * 4);
  int* btot    = (int*)p;      p += align_up((size_t)NB * 4);
  int* bbase   = (int*)p;      p += align_up((size_t)(NB + 1) * 4);
  bf16_t* Wtg1 = (bf16_t*)p;   p += align_up((size_t)CDIM * CDIM * 2);
  bf16_t* Wtg2 = (bf16_t*)p;   p += align_up((size_t)CDIM * CDIM * 2);
  float* gb    = (float*)p;    p += align_up((size_t)NGRAPH * CDIM * 4);
  float* m1    = (float*)p;    p += align_up((size_t)NGRAPH * 500 * 4);
  (void)ws_size; (void)n_in; (void)out_size;

  hipMemsetAsync(gb, 0, (size_t)NGRAPH * CDIM * 4, stream);

  k_wprep<<<64, 256, 0, stream>>>(W1, W2, Wtg1, Wtg2);
  k_phist<<<NBLK, 1024, 0, stream>>>(dst, phist, E, NB);
  k_bscan<<<NB, 256, 0, stream>>>(phist, btot);
  k_boff<<<1, 1024, 0, stream>>>(btot, bbase, NB);
  k_pscatter<<<NBLK, 1024, 0, stream>>>(src, dst, phist, bbase, tmp, E, NB);
  k_csort2<<<NB, 256, 0, stream>>>(tmp, bbase, rowptr, dinv, colx, N, NB, E);

  k_gemm<0><<<512, 256, 0, stream>>>(x, Wtg1, t, N);
  k_agg<0><<<(N + 3) / 4, 256, 0, stream>>>(t, rowptr, colx, dinv, b1, h,
                                            bat, gb, N);
  k_gemm<1><<<512, 256, 0, stream>>>(h, Wtg2, t, N);
  int pwaves = (N + 15) / 16;
  k_agg<1><<<(pwaves + 3) / 4, 256, 0, stream>>>(t, rowptr, colx, dinv, b2,
                                                 (bf16_t*)nullptr, bat, gb, N);

  k_mlp1<<<NGRAPH, 512, 0, stream>>>(gb, bat, N, Wm1, bm1, m1);
  k_mlp23<<<NGRAPH, 128, 0, stream>>>(m1, Wm2, bm2, Wm3, bm3, out);
}

// Round 12
// 353.991 us; speedup vs baseline: 2.3261x; 1.0190x over previous
//
#include <hip/hip_runtime.h>

#define CDIM 128
#define NGRAPH 256
#define BSH 7                 // 128 nodes per bucket
#define BCAP 4096             // LDS sort capacity (mean 2048, +45 sigma)
#define NBLK 256              // blocks for two-pass scatter

typedef unsigned short bf16_t;
typedef __attribute__((ext_vector_type(8))) short bf16x8;  // MFMA A/B frag (4 VGPRs)
typedef __attribute__((ext_vector_type(4))) float f32x4;   // MFMA C/D frag

__device__ __forceinline__ float bflo(unsigned u) { return __uint_as_float(u << 16); }
__device__ __forceinline__ float bfhi(unsigned u) { return __uint_as_float(u & 0xffff0000u); }
__device__ __forceinline__ unsigned short f2bf(float f) {
  unsigned u = __float_as_uint(f);
  u += 0x7fffu + ((u >> 16) & 1u);   // round-to-nearest-even
  return (unsigned short)(u >> 16);
}

// ---------- W prep: fp32 [k][n] -> bf16 transposed [n][k], both layers ----------
__global__ __launch_bounds__(256) void k_wprep(const float* __restrict__ W1,
    const float* __restrict__ W2, bf16_t* __restrict__ Wtg1, bf16_t* __restrict__ Wtg2) {
  int i = blockIdx.x * 256 + threadIdx.x;   // 0..16383
  int n = i >> 7, k = i & 127;
  Wtg1[n * 128 + k] = f2bf(W1[k * 128 + n]);
  Wtg2[n * 128 + k] = f2bf(W2[k * 128 + n]);
}

// pass A: per-block LDS histogram over buckets -> phist[bucket*NBLK + blk]
__global__ __launch_bounds__(1024) void k_phist(const int* __restrict__ dst,
    int* __restrict__ phist, int E, int NB) {
  __shared__ int hist[1024];
  int t = blockIdx.x, tid = threadIdx.x;
  for (int i = tid; i < NB; i += 1024) hist[i] = 0;
  __syncthreads();
  int tile = (E + NBLK - 1) / NBLK;
  int lo = t * tile;
  int hi = lo + tile; if (hi > E) hi = E;
  for (int i = lo + tid; i < hi; i += 1024) atomicAdd(&hist[dst[i] >> BSH], 1);
  __syncthreads();
  for (int i = tid; i < NB; i += 1024) phist[i * NBLK + t] = hist[i];
}

// per-bucket scan: block b scans phist[b*NBLK .. +256] in place (exclusive),
// writes bucket total to btot[b].
__global__ __launch_bounds__(256) void k_bscan(int* __restrict__ phist,
    int* __restrict__ btot) {
  __shared__ int wsum[4];
  int b = blockIdx.x;
  int tid = threadIdx.x, lane = tid & 63, wave = tid >> 6;
  int orig = phist[b * NBLK + tid];
  int v = orig;
#pragma unroll
  for (int ofs = 1; ofs < 64; ofs <<= 1) {
    int u = __shfl_up(v, ofs, 64);
    if (lane >= ofs) v += u;
  }
  if (lane == 63) wsum[wave] = v;
  __syncthreads();
  int add = 0;
#pragma unroll
  for (int w = 0; w < 3; w++) if (w < wave) add += wsum[w];
  int incl = v + add;
  phist[b * NBLK + tid] = incl - orig;   // within-bucket exclusive offset
  if (tid == 255) btot[b] = incl;
}

// single-block exclusive scan of bucket totals -> bbase (bbase[NB] = E)
__global__ __launch_bounds__(1024) void k_boff(const int* __restrict__ bsums,
    int* __restrict__ boffs, int G) {
  __shared__ int sh[1024];
  int tid = threadIdx.x;
  int v = (tid < G) ? bsums[tid] : 0;
  sh[tid] = v;
  __syncthreads();
  for (int ofs = 1; ofs < 1024; ofs <<= 1) {
    int u = (tid >= ofs) ? sh[tid - ofs] : 0;
    __syncthreads();
    sh[tid] += u;
    __syncthreads();
  }
  if (tid < G) boffs[tid] = sh[tid] - v;
  if (tid == G) boffs[G] = (G > 0) ? sh[G - 1] : 0;
}

// pass B: exact-offset scatter, LDS cursors, zero global atomics.
__global__ __launch_bounds__(1024) void k_pscatter(const int* __restrict__ src,
    const int* __restrict__ dst, const int* __restrict__ phist,
    const int* __restrict__ bbase, unsigned* __restrict__ tmp, int E, int NB) {
  __shared__ int cur[1024];
  int t = blockIdx.x, tid = threadIdx.x;
  for (int i = tid; i < NB; i += 1024) cur[i] = bbase[i] + phist[i * NBLK + t];
  __syncthreads();
  int tile = (E + NBLK - 1) / NBLK;
  int lo = t * tile;
  int hi = lo + tile; if (hi > E) hi = E;
  for (int i = lo + tid; i < hi; i += 1024) {
    int d = dst[i];
    int p = atomicAdd(&cur[d >> BSH], 1);
    tmp[p] = (unsigned)src[i] | ((unsigned)(d & 127) << 20);
  }
}

// pass C: per-bucket LDS histogram + scan + counting sort; emits rowptr/dinv/col.
__global__ __launch_bounds__(256) void k_csort2(const unsigned* __restrict__ tmp,
    const int* __restrict__ bbase, int* __restrict__ rowptr, float* __restrict__ dinv,
    int* __restrict__ col, int N, int NB, int E) {
  __shared__ int hist[128];
  __shared__ int sc[128];
  __shared__ int lcur[128];
  __shared__ unsigned buf[BCAP];
  int b = blockIdx.x;
  int n0 = b << BSH;
  int base = bbase[b];
  int cnt = bbase[b + 1] - base;
  int tid = threadIdx.x;
  if (tid < 128) hist[tid] = 0;
  __syncthreads();
  for (int i = tid; i < cnt; i += 256) atomicAdd(&hist[(tmp[base + i] >> 20) & 127], 1);
  __syncthreads();
  if (tid < 128) sc[tid] = hist[tid];
  __syncthreads();
  for (int ofs = 1; ofs < 128; ofs <<= 1) {
    int v = (tid < 128 && tid >= ofs) ? sc[tid - ofs] : 0;
    __syncthreads();
    if (tid < 128) sc[tid] += v;
    __syncthreads();
  }
  if (tid < 128) {
    int excl = sc[tid] - hist[tid];
    lcur[tid] = excl;
    int node = n0 + tid;
    if (node < N) {
      rowptr[node] = base + excl;
      dinv[node] = rsqrtf((float)hist[tid] + 1.0f);
    }
  }
  if (b == 0 && tid == 0) rowptr[N] = E;
  __syncthreads();
  if (cnt <= BCAP) {
    for (int i = tid; i < cnt; i += 256) {
      unsigned pk = tmp[base + i];
      int p = atomicAdd(&lcur[(pk >> 20) & 127], 1);
      buf[p] = pk & 0xFFFFFu;
    }
    __syncthreads();
    for (int i = tid; i < cnt; i += 256) col[base + i] = (int)buf[i];
  } else {
    for (int i = tid; i < cnt; i += 256) {
      unsigned pk = tmp[base + i];
      int p = atomicAdd(&lcur[(pk >> 20) & 127], 1);
      col[base + p] = (int)(pk & 0xFFFFFu);
    }
  }
}

// ---------- MFMA GEMM: [M x 128] @ [128 x 128], bf16 MFMA, fp32 acc, bf16 out ----
#define WSTRIDE 136
template <int BF16IN>
__global__ __launch_bounds__(256) void k_gemm(const void* __restrict__ Ap,
    const bf16_t* __restrict__ Wtg, bf16_t* __restrict__ Co, int M) {
  __shared__ bf16_t Wt[128 * WSTRIDE];
  int tid = threadIdx.x;
  for (int c2 = tid; c2 < 2048; c2 += 256) {   // 2048 x 8-bf16 chunks
    int n = c2 >> 4;
    int k8 = (c2 & 15) << 3;
    *(uint4*)&Wt[n * WSTRIDE + k8] = *(const uint4*)&Wtg[n * 128 + k8];
  }
  __syncthreads();

  int wave = tid >> 6;
  int lane = tid & 63;
  int m = lane & 15;
  int q = lane >> 4;
  int nstrips = (M + 63) >> 6;

  for (int s = blockIdx.x; s < nstrips; s += gridDim.x) {
    int rowA = s * 64 + wave * 16 + m;
    if (rowA > M - 1) rowA = M - 1;
    bf16x8 a[4];
#pragma unroll
    for (int c = 0; c < 4; c++) {
      if (BF16IN) {
        a[c] = *(const bf16x8*)((const bf16_t*)Ap + (size_t)rowA * CDIM + c * 32 + q * 8);
      } else {
        const float* ap = (const float*)Ap + (size_t)rowA * CDIM + c * 32 + q * 8;
        float4 f0 = *(const float4*)ap;
        float4 f1 = *(const float4*)(ap + 4);
        union { bf16x8 v; unsigned short u[8]; } ua;
        ua.u[0] = f2bf(f0.x); ua.u[1] = f2bf(f0.y); ua.u[2] = f2bf(f0.z); ua.u[3] = f2bf(f0.w);
        ua.u[4] = f2bf(f1.x); ua.u[5] = f2bf(f1.y); ua.u[6] = f2bf(f1.z); ua.u[7] = f2bf(f1.w);
        a[c] = ua.v;
      }
    }
#pragma unroll
    for (int t = 0; t < 8; t++) {
      f32x4 acc = {0.f, 0.f, 0.f, 0.f};
#pragma unroll
      for (int c = 0; c < 4; c++) {
        bf16x8 bv = *(const bf16x8*)&Wt[(t * 16 + m) * WSTRIDE + c * 32 + q * 8];
        acc = __builtin_amdgcn_mfma_f32_16x16x32_bf16(a[c], bv, acc, 0, 0, 0);
      }
#pragma unroll
      for (int r = 0; r < 4; r++) {
        int row = s * 64 + wave * 16 + q * 4 + r;
        if (row < M) Co[(size_t)row * CDIM + t * 16 + m] = f2bf(acc[r]);
      }
    }
  }
}

// ---------- gather aggregation + bias + relu; POOL=1 fuses mean-pool ----------
// One wave per node (POOL=0) or 16 consecutive nodes per wave (POOL=1).
// Lanes 0-31 even edges, 32-63 odd edges; uint2 loads (4 ch); 8 edges in flight
// (VGPR<=24 for occupancy — 16-deep unroll measured WORSE: R10 86.6us @ 41% occ).
template <int POOL>
__global__ __launch_bounds__(256) void k_agg(const bf16_t* __restrict__ t,
    const int* __restrict__ rowptr, const int* __restrict__ col,
    const float* __restrict__ dinv, const float* __restrict__ bias,
    bf16_t* __restrict__ out, const int* __restrict__ batch,
    float* __restrict__ gsum, int N) {
  int wave = threadIdx.x >> 6;
  int lane = threadIdx.x & 63;
  int half = lane >> 5;
  int c = lane & 31;
  const uint2* tp = (const uint2*)t;
  float4 bb = ((const float4*)bias)[c];
  int n0, nEnd;
  if (POOL) { n0 = (blockIdx.x * 4 + wave) * 16; nEnd = n0 + 16; }
  else      { n0 = blockIdx.x * 4 + wave;        nEnd = n0 + 1; }
  if (n0 >= N) return;
  if (nEnd > N) nEnd = N;
  float p0 = 0.f, p1 = 0.f, p2 = 0.f, p3 = 0.f;
  int curb = POOL ? batch[n0] : 0;

  for (int node = n0; node < nEnd; node++) {
    float di = dinv[node];
    uint2 sv = tp[(size_t)node * 32 + c];
    float sw = (half == 0) ? di : 0.f;   // self term counted once
    float a0 = bflo(sv.x) * sw, a1 = bfhi(sv.x) * sw;
    float a2 = bflo(sv.y) * sw, a3 = bfhi(sv.y) * sw;
    int beg = rowptr[node], end = rowptr[node + 1];
    for (int base = beg; base < end; base += 64) {
      int rem = end - base;
      int cnt = rem < 64 ? rem : 64;
      int sL = 0; float wL = 0.f;
      if (lane < cnt) { sL = col[base + lane]; wL = dinv[sL]; }
      for (int k = 0; k < cnt; k += 8) {
        int j0 = k + half, j1 = k + 2 + half, j2 = k + 4 + half, j3 = k + 6 + half;
        int s0 = __shfl(sL, j0, 64); float w0 = __shfl(wL, j0, 64);
        int s1 = __shfl(sL, j1, 64); float w1 = __shfl(wL, j1, 64);
        int s2 = __shfl(sL, j2, 64); float w2 = __shfl(wL, j2, 64);
        int s3 = __shfl(sL, j3, 64); float w3 = __shfl(wL, j3, 64);
        if (j0 >= cnt) { s0 = node; w0 = 0.f; }
        if (j1 >= cnt) { s1 = node; w1 = 0.f; }
        if (j2 >= cnt) { s2 = node; w2 = 0.f; }
        if (j3 >= cnt) { s3 = node; w3 = 0.f; }
        uint2 v0 = tp[(size_t)s0 * 32 + c];
        uint2 v1 = tp[(size_t)s1 * 32 + c];
        uint2 v2 = tp[(size_t)s2 * 32 + c];
        uint2 v3 = tp[(size_t)s3 * 32 + c];
        a0 = fmaf(bflo(v0.x), w0, a0); a1 = fmaf(bfhi(v0.x), w0, a1);
        a2 = fmaf(bflo(v0.y), w0, a2); a3 = fmaf(bfhi(v0.y), w0, a3);
        a0 = fmaf(bflo(v1.x), w1, a0); a1 = fmaf(bfhi(v1.x), w1, a1);
        a2 = fmaf(bflo(v1.y), w1, a2); a3 = fmaf(bfhi(v1.y), w1, a3);
        a0 = fmaf(bflo(v2.x), w2, a0); a1 = fmaf(bfhi(v2.x), w2, a1);
        a2 = fmaf(bflo(v2.y), w2, a2); a3 = fmaf(bfhi(v2.y), w2, a3);
        a0 = fmaf(bflo(v3.x), w3, a0); a1 = fmaf(bfhi(v3.x), w3, a1);
        a2 = fmaf(bflo(v3.y), w3, a2); a3 = fmaf(bfhi(v3.y), w3, a3);
      }
    }
    a0 += __shfl_xor(a0, 32, 64);
    a1 += __shfl_xor(a1, 32, 64);
    a2 += __shfl_xor(a2, 32, 64);
    a3 += __shfl_xor(a3, 32, 64);
    if (half == 0) {
      float o0 = fmaxf(fmaf(di, a0, bb.x), 0.f);
      float o1 = fmaxf(fmaf(di, a1, bb.y), 0.f);
      float o2 = fmaxf(fmaf(di, a2, bb.z), 0.f);
      float o3 = fmaxf(fmaf(di, a3, bb.w), 0.f);
      if (!POOL) {
        uint2 o;
        o.x = ((unsigned)f2bf(o1) << 16) | f2bf(o0);
        o.y = ((unsigned)f2bf(o3) << 16) | f2bf(o2);
        ((uint2*)(out + (size_t)node * CDIM))[c] = o;
      } else {
        int b = batch[node];
        if (b != curb) {
          atomicAdd(&gsum[curb * CDIM + c * 4 + 0], p0);
          atomicAdd(&gsum[curb * CDIM + c * 4 + 1], p1);
          atomicAdd(&gsum[curb * CDIM + c * 4 + 2], p2);
          atomicAdd(&gsum[curb * CDIM + c * 4 + 3], p3);
          curb = b; p0 = p1 = p2 = p3 = 0.f;
        }
        // accumulate in bf16-rounded precision to match the unfused reference path
        p0 += __uint_as_float((unsigned)f2bf(o0) << 16);
        p1 += __uint_as_float((unsigned)f2bf(o1) << 16);
        p2 += __uint_as_float((unsigned)f2bf(o2) << 16);
        p3 += __uint_as_float((unsigned)f2bf(o3) << 16);
      }
    }
  }
  if (POOL && half == 0) {
    atomicAdd(&gsum[curb * CDIM + c * 4 + 0], p0);
    atomicAdd(&gsum[curb * CDIM + c * 4 + 1], p1);
    atomicAdd(&gsum[curb * CDIM + c * 4 + 2], p2);
    atomicAdd(&gsum[curb * CDIM + c * 4 + 3], p3);
  }
}

// ---------- MLP head (mlp1 also divides the pooled sum by the node count) ----
__global__ __launch_bounds__(512) void k_mlp1(const float* __restrict__ g,
    const int* __restrict__ batch, int N,
    const float* __restrict__ W, const float* __restrict__ b, float* __restrict__ o) {
  __shared__ float gs[CDIM];
  int bi = blockIdx.x, tid = threadIdx.x;
  if (tid < CDIM) {
    int lo = 0, hi = N;
    while (lo < hi) { int mid = (lo + hi) >> 1; if (batch[mid] < bi) lo = mid + 1; else hi = mid; }
    int s = lo;
    lo = 0; hi = N;
    int key = bi + 1;
    while (lo < hi) { int mid = (lo + hi) >> 1; if (batch[mid] < key) lo = mid + 1; else hi = mid; }
    float inv = 1.f / fmaxf((float)(lo - s), 1.f);
    gs[tid] = g[bi * CDIM + tid] * inv;
  }
  __syncthreads();
  if (tid < 500) {
    float acc = b[tid];
#pragma unroll 4
    for (int k = 0; k < CDIM; k++) acc = fmaf(gs[k], W[k * 500 + tid], acc);
    o[bi * 500 + tid] = fmaxf(acc, 0.f);
  }
}

// fused mlp2 (relu) + mlp3 (dot)
__global__ __launch_bounds__(128) void k_mlp23(const float* __restrict__ a,
    const float* __restrict__ W2m, const float* __restrict__ b2m,
    const float* __restrict__ w3, const float* __restrict__ b3,
    float* __restrict__ o) {
  __shared__ float as[500];
  __shared__ float m2s[100];
  int bi = blockIdx.x, tid = threadIdx.x;
  for (int k = tid; k < 500; k += 128) as[k] = a[bi * 500 + k];
  __syncthreads();
  if (tid < 100) {
    float acc = b2m[tid];
    for (int k = 0; k < 500; k++) acc = fmaf(as[k], W2m[k * 100 + tid], acc);
    m2s[tid] = fmaxf(acc, 0.f) * w3[tid];
  }
  __syncthreads();
  if (tid < 64) {
    float v = m2s[tid] + ((tid + 64 < 100) ? m2s[tid + 64] : 0.f);
#pragma unroll
    for (int ofs = 32; ofs > 0; ofs >>= 1) v += __shfl_down(v, ofs, 64);
    if (tid == 0) o[bi] = v + b3[0];
  }
}

static inline size_t align_up(size_t v) { return (v + 255) & ~(size_t)255; }

extern "C" void kernel_launch(void* const* d_in, const int* in_sizes, int n_in,
                              void* d_out, int out_size, void* d_ws, size_t ws_size,
                              hipStream_t stream) {
  const float* x   = (const float*)d_in[0];
  const int*   ei  = (const int*)d_in[1];
  const int*   bat = (const int*)d_in[2];
  const float* W1  = (const float*)d_in[3];
  const float* b1  = (const float*)d_in[4];
  const float* W2  = (const float*)d_in[5];
  const float* b2  = (const float*)d_in[6];
  const float* Wm1 = (const float*)d_in[7];
  const float* bm1 = (const float*)d_in[8];
  const float* Wm2 = (const float*)d_in[9];
  const float* bm2 = (const float*)d_in[10];
  const float* Wm3 = (const float*)d_in[11];
  const float* bm3 = (const float*)d_in[12];
  float* out = (float*)d_out;

  const int E = in_sizes[1] / 2;
  const int N = in_sizes[2];
  const int* src = ei;
  const int* dst = ei + E;
  const int NB = (N + 127) >> BSH;
  const int M  = NB * NBLK;              // phist elements

  char* p = (char*)d_ws;
  bf16_t* t    = (bf16_t*)p;   p += align_up((size_t)N * CDIM * 2);
  bf16_t* h    = (bf16_t*)p;   p += align_up((size_t)N * CDIM * 2);
  int* rowptr  = (int*)p;      p += align_up((size_t)(N + 1) * 4);
  int* colx    = (int*)p;      p += align_up((size_t)E * 4);
  unsigned* tmp= (unsigned*)p; p += align_up((size_t)E * 4);
  float* dinv  = (float*)p;    p += align_up((size_t)N * 4);
  int* phist   = (int*)p;      p += align_up((size_t)M * 4);
  int* btot    = (int*)p;      p += align_up((size_t)NB * 4);
  int* bbase   = (int*)p;      p += align_up((size_t)(NB + 1) * 4);
  bf16_t* Wtg1 = (bf16_t*)p;   p += align_up((size_t)CDIM * CDIM * 2);
  bf16_t* Wtg2 = (bf16_t*)p;   p += align_up((size_t)CDIM * CDIM * 2);
  float* gb    = (float*)p;    p += align_up((size_t)NGRAPH * CDIM * 4);
  float* m1    = (float*)p;    p += align_up((size_t)NGRAPH * 500 * 4);
  (void)ws_size; (void)n_in; (void)out_size;

  hipMemsetAsync(gb, 0, (size_t)NGRAPH * CDIM * 4, stream);

  k_wprep<<<64, 256, 0, stream>>>(W1, W2, Wtg1, Wtg2);
  k_phist<<<NBLK, 1024, 0, stream>>>(dst, phist, E, NB);
  k_bscan<<<NB, 256, 0, stream>>>(phist, btot);
  k_boff<<<1, 1024, 0, stream>>>(btot, bbase, NB);
  k_pscatter<<<NBLK, 1024, 0, stream>>>(src, dst, phist, bbase, tmp, E, NB);
  k_csort2<<<NB, 256, 0, stream>>>(tmp, bbase, rowptr, dinv, colx, N, NB, E);

  k_gemm<0><<<512, 256, 0, stream>>>(x, Wtg1, t, N);
  k_agg<0><<<(N + 3) / 4, 256, 0, stream>>>(t, rowptr, colx, dinv, b1, h,
                                            bat, gb, N);
  k_gemm<1><<<512, 256, 0, stream>>>(h, Wtg2, t, N);
  int pwaves = (N + 15) / 16;
  k_agg<1><<<(pwaves + 3) / 4, 256, 0, stream>>>(t, rowptr, colx, dinv, b2,
                                                 (bf16_t*)nullptr, bat, gb, N);

  k_mlp1<<<NGRAPH, 512, 0, stream>>>(gb, bat, N, Wm1, bm1, m1);
  k_mlp23<<<NGRAPH, 128, 0, stream>>>(m1, Wm2, bm2, Wm3, bm3, out);
}

// Round 13
// 349.306 us; speedup vs baseline: 2.3573x; 1.0134x over previous
//
#include <hip/hip_runtime.h>

#define CDIM 128
#define NGRAPH 256
#define BSH 7                 // 128 nodes per bucket
#define BCAP 4096             // LDS sort capacity (mean 2048, +45 sigma)
#define NBLK 256              // blocks for two-pass scatter

typedef unsigned short bf16_t;
typedef __attribute__((ext_vector_type(8))) short bf16x8;  // MFMA A/B frag (4 VGPRs)
typedef __attribute__((ext_vector_type(4))) float f32x4;   // MFMA C/D frag

__device__ __forceinline__ float bflo(unsigned u) { return __uint_as_float(u << 16); }
__device__ __forceinline__ float bfhi(unsigned u) { return __uint_as_float(u & 0xffff0000u); }
__device__ __forceinline__ unsigned short f2bf(float f) {
  unsigned u = __float_as_uint(f);
  u += 0x7fffu + ((u >> 16) & 1u);   // round-to-nearest-even
  return (unsigned short)(u >> 16);
}

// ---------- W prep: fp32 [k][n] -> bf16 transposed [n][k], both layers ----------
__global__ __launch_bounds__(256) void k_wprep(const float* __restrict__ W1,
    const float* __restrict__ W2, bf16_t* __restrict__ Wtg1, bf16_t* __restrict__ Wtg2) {
  int i = blockIdx.x * 256 + threadIdx.x;   // 0..16383
  int n = i >> 7, k = i & 127;
  Wtg1[n * 128 + k] = f2bf(W1[k * 128 + n]);
  Wtg2[n * 128 + k] = f2bf(W2[k * 128 + n]);
}

// pass A: per-block LDS histogram over buckets -> phist[bucket*NBLK + blk]
__global__ __launch_bounds__(1024) void k_phist(const int* __restrict__ dst,
    int* __restrict__ phist, int E, int NB) {
  __shared__ int hist[1024];
  int t = blockIdx.x, tid = threadIdx.x;
  for (int i = tid; i < NB; i += 1024) hist[i] = 0;
  __syncthreads();
  int tile = (E + NBLK - 1) / NBLK;
  int lo = t * tile;
  int hi = lo + tile; if (hi > E) hi = E;
  for (int i = lo + tid; i < hi; i += 1024) atomicAdd(&hist[dst[i] >> BSH], 1);
  __syncthreads();
  for (int i = tid; i < NB; i += 1024) phist[i * NBLK + t] = hist[i];
}

// per-bucket scan: block b scans phist[b*NBLK .. +256] in place (exclusive),
// writes bucket total to btot[b].
__global__ __launch_bounds__(256) void k_bscan(int* __restrict__ phist,
    int* __restrict__ btot) {
  __shared__ int wsum[4];
  int b = blockIdx.x;
  int tid = threadIdx.x, lane = tid & 63, wave = tid >> 6;
  int orig = phist[b * NBLK + tid];
  int v = orig;
#pragma unroll
  for (int ofs = 1; ofs < 64; ofs <<= 1) {
    int u = __shfl_up(v, ofs, 64);
    if (lane >= ofs) v += u;
  }
  if (lane == 63) wsum[wave] = v;
  __syncthreads();
  int add = 0;
#pragma unroll
  for (int w = 0; w < 3; w++) if (w < wave) add += wsum[w];
  int incl = v + add;
  phist[b * NBLK + tid] = incl - orig;   // within-bucket exclusive offset
  if (tid == 255) btot[b] = incl;
}

// single-block exclusive scan of bucket totals -> bbase (bbase[NB] = E)
__global__ __launch_bounds__(1024) void k_boff(const int* __restrict__ bsums,
    int* __restrict__ boffs, int G) {
  __shared__ int sh[1024];
  int tid = threadIdx.x;
  int v = (tid < G) ? bsums[tid] : 0;
  sh[tid] = v;
  __syncthreads();
  for (int ofs = 1; ofs < 1024; ofs <<= 1) {
    int u = (tid >= ofs) ? sh[tid - ofs] : 0;
    __syncthreads();
    sh[tid] += u;
    __syncthreads();
  }
  if (tid < G) boffs[tid] = sh[tid] - v;
  if (tid == G) boffs[G] = (G > 0) ? sh[G - 1] : 0;
}

// pass B: exact-offset scatter, LDS cursors, zero global atomics.
__global__ __launch_bounds__(1024) void k_pscatter(const int* __restrict__ src,
    const int* __restrict__ dst, const int* __restrict__ phist,
    const int* __restrict__ bbase, unsigned* __restrict__ tmp, int E, int NB) {
  __shared__ int cur[1024];
  int t = blockIdx.x, tid = threadIdx.x;
  for (int i = tid; i < NB; i += 1024) cur[i] = bbase[i] + phist[i * NBLK + t];
  __syncthreads();
  int tile = (E + NBLK - 1) / NBLK;
  int lo = t * tile;
  int hi = lo + tile; if (hi > E) hi = E;
  for (int i = lo + tid; i < hi; i += 1024) {
    int d = dst[i];
    int p = atomicAdd(&cur[d >> BSH], 1);
    tmp[p] = (unsigned)src[i] | ((unsigned)(d & 127) << 20);
  }
}

// pass C: per-bucket LDS histogram + scan + counting sort; emits rowptr/dinv/col.
__global__ __launch_bounds__(256) void k_csort2(const unsigned* __restrict__ tmp,
    const int* __restrict__ bbase, int* __restrict__ rowptr, float* __restrict__ dinv,
    int* __restrict__ col, int N, int NB, int E) {
  __shared__ int hist[128];
  __shared__ int sc[128];
  __shared__ int lcur[128];
  __shared__ unsigned buf[BCAP];
  int b = blockIdx.x;
  int n0 = b << BSH;
  int base = bbase[b];
  int cnt = bbase[b + 1] - base;
  int tid = threadIdx.x;
  if (tid < 128) hist[tid] = 0;
  __syncthreads();
  for (int i = tid; i < cnt; i += 256) atomicAdd(&hist[(tmp[base + i] >> 20) & 127], 1);
  __syncthreads();
  if (tid < 128) sc[tid] = hist[tid];
  __syncthreads();
  for (int ofs = 1; ofs < 128; ofs <<= 1) {
    int v = (tid < 128 && tid >= ofs) ? sc[tid - ofs] : 0;
    __syncthreads();
    if (tid < 128) sc[tid] += v;
    __syncthreads();
  }
  if (tid < 128) {
    int excl = sc[tid] - hist[tid];
    lcur[tid] = excl;
    int node = n0 + tid;
    if (node < N) {
      rowptr[node] = base + excl;
      dinv[node] = rsqrtf((float)hist[tid] + 1.0f);
    }
  }
  if (b == 0 && tid == 0) rowptr[N] = E;
  __syncthreads();
  if (cnt <= BCAP) {
    for (int i = tid; i < cnt; i += 256) {
      unsigned pk = tmp[base + i];
      int p = atomicAdd(&lcur[(pk >> 20) & 127], 1);
      buf[p] = pk & 0xFFFFFu;
    }
    __syncthreads();
    for (int i = tid; i < cnt; i += 256) col[base + i] = (int)buf[i];
  } else {
    for (int i = tid; i < cnt; i += 256) {
      unsigned pk = tmp[base + i];
      int p = atomicAdd(&lcur[(pk >> 20) & 127], 1);
      col[base + p] = (int)(pk & 0xFFFFFu);
    }
  }
}

// ---------- MFMA GEMM: [M x 128] @ [128 x 128], bf16 MFMA, fp32 acc, bf16 out ----
#define WSTRIDE 136
template <int BF16IN>
__global__ __launch_bounds__(256) void k_gemm(const void* __restrict__ Ap,
    const bf16_t* __restrict__ Wtg, bf16_t* __restrict__ Co, int M) {
  __shared__ bf16_t Wt[128 * WSTRIDE];
  int tid = threadIdx.x;
  for (int c2 = tid; c2 < 2048; c2 += 256) {   // 2048 x 8-bf16 chunks
    int n = c2 >> 4;
    int k8 = (c2 & 15) << 3;
    *(uint4*)&Wt[n * WSTRIDE + k8] = *(const uint4*)&Wtg[n * 128 + k8];
  }
  __syncthreads();

  int wave = tid >> 6;
  int lane = tid & 63;
  int m = lane & 15;
  int q = lane >> 4;
  int nstrips = (M + 63) >> 6;

  for (int s = blockIdx.x; s < nstrips; s += gridDim.x) {
    int rowA = s * 64 + wave * 16 + m;
    if (rowA > M - 1) rowA = M - 1;
    bf16x8 a[4];
#pragma unroll
    for (int c = 0; c < 4; c++) {
      if (BF16IN) {
        a[c] = *(const bf16x8*)((const bf16_t*)Ap + (size_t)rowA * CDIM + c * 32 + q * 8);
      } else {
        const float* ap = (const float*)Ap + (size_t)rowA * CDIM + c * 32 + q * 8;
        float4 f0 = *(const float4*)ap;
        float4 f1 = *(const float4*)(ap + 4);
        union { bf16x8 v; unsigned short u[8]; } ua;
        ua.u[0] = f2bf(f0.x); ua.u[1] = f2bf(f0.y); ua.u[2] = f2bf(f0.z); ua.u[3] = f2bf(f0.w);
        ua.u[4] = f2bf(f1.x); ua.u[5] = f2bf(f1.y); ua.u[6] = f2bf(f1.z); ua.u[7] = f2bf(f1.w);
        a[c] = ua.v;
      }
    }
#pragma unroll
    for (int t = 0; t < 8; t++) {
      f32x4 acc = {0.f, 0.f, 0.f, 0.f};
#pragma unroll
      for (int c = 0; c < 4; c++) {
        bf16x8 bv = *(const bf16x8*)&Wt[(t * 16 + m) * WSTRIDE + c * 32 + q * 8];
        acc = __builtin_amdgcn_mfma_f32_16x16x32_bf16(a[c], bv, acc, 0, 0, 0);
      }
#pragma unroll
      for (int r = 0; r < 4; r++) {
        int row = s * 64 + wave * 16 + q * 4 + r;
        if (row < M) Co[(size_t)row * CDIM + t * 16 + m] = f2bf(acc[r]);
      }
    }
  }
}

// ---------- layer-1 gather aggregation (verbatim R9 structure: VGPR 24) -------
// One wave per node; lanes 0-31 even edges, 32-63 odd; uint2 loads (4 ch);
// 8 edges in flight. Writes bf16 h rows.
__global__ __launch_bounds__(256) void k_agg0(const bf16_t* __restrict__ t,
    const int* __restrict__ rowptr, const int* __restrict__ col,
    const float* __restrict__ dinv, const float* __restrict__ bias,
    bf16_t* __restrict__ out, int N) {
  int wave = threadIdx.x >> 6;
  int lane = threadIdx.x & 63;
  int node = blockIdx.x * 4 + wave;
  if (node >= N) return;
  int half = lane >> 5;
  int c = lane & 31;
  const uint2* tp = (const uint2*)t;
  float di = dinv[node];
  uint2 sv = tp[(size_t)node * 32 + c];
  float sw = (half == 0) ? di : 0.f;
  float a0 = bflo(sv.x) * sw, a1 = bfhi(sv.x) * sw;
  float a2 = bflo(sv.y) * sw, a3 = bfhi(sv.y) * sw;
  int beg = rowptr[node], end = rowptr[node + 1];
  for (int base = beg; base < end; base += 64) {
    int rem = end - base;
    int cnt = rem < 64 ? rem : 64;
    int sL = 0; float wL = 0.f;
    if (lane < cnt) { sL = col[base + lane]; wL = dinv[sL]; }
    for (int k = 0; k < cnt; k += 8) {
      int j0 = k + half, j1 = k + 2 + half, j2 = k + 4 + half, j3 = k + 6 + half;
      int s0 = __shfl(sL, j0, 64); float w0 = __shfl(wL, j0, 64);
      int s1 = __shfl(sL, j1, 64); float w1 = __shfl(wL, j1, 64);
      int s2 = __shfl(sL, j2, 64); float w2 = __shfl(wL, j2, 64);
      int s3 = __shfl(sL, j3, 64); float w3 = __shfl(wL, j3, 64);
      if (j0 >= cnt) { s0 = node; w0 = 0.f; }
      if (j1 >= cnt) { s1 = node; w1 = 0.f; }
      if (j2 >= cnt) { s2 = node; w2 = 0.f; }
      if (j3 >= cnt) { s3 = node; w3 = 0.f; }
      uint2 v0 = tp[(size_t)s0 * 32 + c];
      uint2 v1 = tp[(size_t)s1 * 32 + c];
      uint2 v2 = tp[(size_t)s2 * 32 + c];
      uint2 v3 = tp[(size_t)s3 * 32 + c];
      a0 = fmaf(bflo(v0.x), w0, a0); a1 = fmaf(bfhi(v0.x), w0, a1);
      a2 = fmaf(bflo(v0.y), w0, a2); a3 = fmaf(bfhi(v0.y), w0, a3);
      a0 = fmaf(bflo(v1.x), w1, a0); a1 = fmaf(bfhi(v1.x), w1, a1);
      a2 = fmaf(bflo(v1.y), w1, a2); a3 = fmaf(bfhi(v1.y), w1, a3);
      a0 = fmaf(bflo(v2.x), w2, a0); a1 = fmaf(bfhi(v2.x), w2, a1);
      a2 = fmaf(bflo(v2.y), w2, a2); a3 = fmaf(bfhi(v2.y), w2, a3);
      a0 = fmaf(bflo(v3.x), w3, a0); a1 = fmaf(bfhi(v3.x), w3, a1);
      a2 = fmaf(bflo(v3.y), w3, a2); a3 = fmaf(bfhi(v3.y), w3, a3);
    }
  }
  a0 += __shfl_xor(a0, 32, 64);
  a1 += __shfl_xor(a1, 32, 64);
  a2 += __shfl_xor(a2, 32, 64);
  a3 += __shfl_xor(a3, 32, 64);
  if (half == 0) {
    float4 bb = ((const float4*)bias)[c];
    float o0 = fmaxf(fmaf(di, a0, bb.x), 0.f);
    float o1 = fmaxf(fmaf(di, a1, bb.y), 0.f);
    float o2 = fmaxf(fmaf(di, a2, bb.z), 0.f);
    float o3 = fmaxf(fmaf(di, a3, bb.w), 0.f);
    uint2 o;
    o.x = ((unsigned)f2bf(o1) << 16) | f2bf(o0);
    o.y = ((unsigned)f2bf(o3) << 16) | f2bf(o2);
    ((uint2*)(out + (size_t)node * CDIM))[c] = o;
  }
}

// ---------- layer-2 gather aggregation fused with mean-pool -------------------
// 16 consecutive nodes per wave; pooled sums in registers; atomic flush on
// graph change. bf16-rounded accumulation matches the unfused reference path.
__global__ __launch_bounds__(256) void k_aggp(const bf16_t* __restrict__ t,
    const int* __restrict__ rowptr, const int* __restrict__ col,
    const float* __restrict__ dinv, const float* __restrict__ bias,
    const int* __restrict__ batch, float* __restrict__ gsum, int N) {
  int wave = threadIdx.x >> 6;
  int lane = threadIdx.x & 63;
  int half = lane >> 5;
  int c = lane & 31;
  const uint2* tp = (const uint2*)t;
  float4 bb = ((const float4*)bias)[c];
  int n0 = (blockIdx.x * 4 + wave) * 16;
  if (n0 >= N) return;
  int nEnd = n0 + 16; if (nEnd > N) nEnd = N;
  float p0 = 0.f, p1 = 0.f, p2 = 0.f, p3 = 0.f;
  int curb = batch[n0];

  for (int node = n0; node < nEnd; node++) {
    float di = dinv[node];
    uint2 sv = tp[(size_t)node * 32 + c];
    float sw = (half == 0) ? di : 0.f;
    float a0 = bflo(sv.x) * sw, a1 = bfhi(sv.x) * sw;
    float a2 = bflo(sv.y) * sw, a3 = bfhi(sv.y) * sw;
    int beg = rowptr[node], end = rowptr[node + 1];
    for (int base = beg; base < end; base += 64) {
      int rem = end - base;
      int cnt = rem < 64 ? rem : 64;
      int sL = 0; float wL = 0.f;
      if (lane < cnt) { sL = col[base + lane]; wL = dinv[sL]; }
      for (int k = 0; k < cnt; k += 8) {
        int j0 = k + half, j1 = k + 2 + half, j2 = k + 4 + half, j3 = k + 6 + half;
        int s0 = __shfl(sL, j0, 64); float w0 = __shfl(wL, j0, 64);
        int s1 = __shfl(sL, j1, 64); float w1 = __shfl(wL, j1, 64);
        int s2 = __shfl(sL, j2, 64); float w2 = __shfl(wL, j2, 64);
        int s3 = __shfl(sL, j3, 64); float w3 = __shfl(wL, j3, 64);
        if (j0 >= cnt) { s0 = node; w0 = 0.f; }
        if (j1 >= cnt) { s1 = node; w1 = 0.f; }
        if (j2 >= cnt) { s2 = node; w2 = 0.f; }
        if (j3 >= cnt) { s3 = node; w3 = 0.f; }
        uint2 v0 = tp[(size_t)s0 * 32 + c];
        uint2 v1 = tp[(size_t)s1 * 32 + c];
        uint2 v2 = tp[(size_t)s2 * 32 + c];
        uint2 v3 = tp[(size_t)s3 * 32 + c];
        a0 = fmaf(bflo(v0.x), w0, a0); a1 = fmaf(bfhi(v0.x), w0, a1);
        a2 = fmaf(bflo(v0.y), w0, a2); a3 = fmaf(bfhi(v0.y), w0, a3);
        a0 = fmaf(bflo(v1.x), w1, a0); a1 = fmaf(bfhi(v1.x), w1, a1);
        a2 = fmaf(bflo(v1.y), w1, a2); a3 = fmaf(bfhi(v1.y), w1, a3);
        a0 = fmaf(bflo(v2.x), w2, a0); a1 = fmaf(bfhi(v2.x), w2, a1);
        a2 = fmaf(bflo(v2.y), w2, a2); a3 = fmaf(bfhi(v2.y), w2, a3);
        a0 = fmaf(bflo(v3.x), w3, a0); a1 = fmaf(bfhi(v3.x), w3, a1);
        a2 = fmaf(bflo(v3.y), w3, a2); a3 = fmaf(bfhi(v3.y), w3, a3);
      }
    }
    a0 += __shfl_xor(a0, 32, 64);
    a1 += __shfl_xor(a1, 32, 64);
    a2 += __shfl_xor(a2, 32, 64);
    a3 += __shfl_xor(a3, 32, 64);
    if (half == 0) {
      float o0 = fmaxf(fmaf(di, a0, bb.x), 0.f);
      float o1 = fmaxf(fmaf(di, a1, bb.y), 0.f);
      float o2 = fmaxf(fmaf(di, a2, bb.z), 0.f);
      float o3 = fmaxf(fmaf(di, a3, bb.w), 0.f);
      int b = batch[node];
      if (b != curb) {
        atomicAdd(&gsum[curb * CDIM + c * 4 + 0], p0);
        atomicAdd(&gsum[curb * CDIM + c * 4 + 1], p1);
        atomicAdd(&gsum[curb * CDIM + c * 4 + 2], p2);
        atomicAdd(&gsum[curb * CDIM + c * 4 + 3], p3);
        curb = b; p0 = p1 = p2 = p3 = 0.f;
      }
      p0 += __uint_as_float((unsigned)f2bf(o0) << 16);
      p1 += __uint_as_float((unsigned)f2bf(o1) << 16);
      p2 += __uint_as_float((unsigned)f2bf(o2) << 16);
      p3 += __uint_as_float((unsigned)f2bf(o3) << 16);
    }
  }
  if (half == 0) {
    atomicAdd(&gsum[curb * CDIM + c * 4 + 0], p0);
    atomicAdd(&gsum[curb * CDIM + c * 4 + 1], p1);
    atomicAdd(&gsum[curb * CDIM + c * 4 + 2], p2);
    atomicAdd(&gsum[curb * CDIM + c * 4 + 3], p3);
  }
}

// ---------- MLP head (mlp1 also divides the pooled sum by the node count) ----
__global__ __launch_bounds__(512) void k_mlp1(const float* __restrict__ g,
    const int* __restrict__ batch, int N,
    const float* __restrict__ W, const float* __restrict__ b, float* __restrict__ o) {
  __shared__ float gs[CDIM];
  int bi = blockIdx.x, tid = threadIdx.x;
  if (tid < CDIM) {
    int lo = 0, hi = N;
    while (lo < hi) { int mid = (lo + hi) >> 1; if (batch[mid] < bi) lo = mid + 1; else hi = mid; }
    int s = lo;
    lo = 0; hi = N;
    int key = bi + 1;
    while (lo < hi) { int mid = (lo + hi) >> 1; if (batch[mid] < key) lo = mid + 1; else hi = mid; }
    float inv = 1.f / fmaxf((float)(lo - s), 1.f);
    gs[tid] = g[bi * CDIM + tid] * inv;
  }
  __syncthreads();
  if (tid < 500) {
    float acc = b[tid];
#pragma unroll 4
    for (int k = 0; k < CDIM; k++) acc = fmaf(gs[k], W[k * 500 + tid], acc);
    o[bi * 500 + tid] = fmaxf(acc, 0.f);
  }
}

// fused mlp2 (relu) + mlp3 (dot)
__global__ __launch_bounds__(128) void k_mlp23(const float* __restrict__ a,
    const float* __restrict__ W2m, const float* __restrict__ b2m,
    const float* __restrict__ w3, const float* __restrict__ b3,
    float* __restrict__ o) {
  __shared__ float as[500];
  __shared__ float m2s[100];
  int bi = blockIdx.x, tid = threadIdx.x;
  for (int k = tid; k < 500; k += 128) as[k] = a[bi * 500 + k];
  __syncthreads();
  if (tid < 100) {
    float acc = b2m[tid];
    for (int k = 0; k < 500; k++) acc = fmaf(as[k], W2m[k * 100 + tid], acc);
    m2s[tid] = fmaxf(acc, 0.f) * w3[tid];
  }
  __syncthreads();
  if (tid < 64) {
    float v = m2s[tid] + ((tid + 64 < 100) ? m2s[tid + 64] : 0.f);
#pragma unroll
    for (int ofs = 32; ofs > 0; ofs >>= 1) v += __shfl_down(v, ofs, 64);
    if (tid == 0) o[bi] = v + b3[0];
  }
}

static inline size_t align_up(size_t v) { return (v + 255) & ~(size_t)255; }

extern "C" void kernel_launch(void* const* d_in, const int* in_sizes, int n_in,
                              void* d_out, int out_size, void* d_ws, size_t ws_size,
                              hipStream_t stream) {
  const float* x   = (const float*)d_in[0];
  const int*   ei  = (const int*)d_in[1];
  const int*   bat = (const int*)d_in[2];
  const float* W1  = (const float*)d_in[3];
  const float* b1  = (const float*)d_in[4];
  const float* W2  = (const float*)d_in[5];
  const float* b2  = (const float*)d_in[6];
  const float* Wm1 = (const float*)d_in[7];
  const float* bm1 = (const float*)d_in[8];
  const float* Wm2 = (const float*)d_in[9];
  const float* bm2 = (const float*)d_in[10];
  const float* Wm3 = (const float*)d_in[11];
  const float* bm3 = (const float*)d_in[12];
  float* out = (float*)d_out;

  const int E = in_sizes[1] / 2;
  const int N = in_sizes[2];
  const int* src = ei;
  const int* dst = ei + E;
  const int NB = (N + 127) >> BSH;
  const int M  = NB * NBLK;              // phist elements

  char* p = (char*)d_ws;
  bf16_t* t    = (bf16_t*)p;   p += align_up((size_t)N * CDIM * 2);
  bf16_t* h    = (bf16_t*)p;   p += align_up((size_t)N * CDIM * 2);
  int* rowptr  = (int*)p;      p += align_up((size_t)(N + 1) * 4);
  int* colx    = (int*)p;      p += align_up((size_t)E * 4);
  unsigned* tmp= (unsigned*)p; p += align_up((size_t)E * 4);
  float* dinv  = (float*)p;    p += align_up((size_t)N * 4);
  int* phist   = (int*)p;      p += align_up((size_t)M * 4);
  int* btot    = (int*)p;      p += align_up((size_t)NB * 4);
  int* bbase   = (int*)p;      p += align_up((size_t)(NB + 1) * 4);
  bf16_t* Wtg1 = (bf16_t*)p;   p += align_up((size_t)CDIM * CDIM * 2);
  bf16_t* Wtg2 = (bf16_t*)p;   p += align_up((size_t)CDIM * CDIM * 2);
  float* gb    = (float*)p;    p += align_up((size_t)NGRAPH * CDIM * 4);
  float* m1    = (float*)p;    p += align_up((size_t)NGRAPH * 500 * 4);
  (void)ws_size; (void)n_in; (void)out_size;

  hipMemsetAsync(gb, 0, (size_t)NGRAPH * CDIM * 4, stream);

  k_wprep<<<64, 256, 0, stream>>>(W1, W2, Wtg1, Wtg2);
  k_phist<<<NBLK, 1024, 0, stream>>>(dst, phist, E, NB);
  k_bscan<<<NB, 256, 0, stream>>>(phist, btot);
  k_boff<<<1, 1024, 0, stream>>>(btot, bbase, NB);
  k_pscatter<<<NBLK, 1024, 0, stream>>>(src, dst, phist, bbase, tmp, E, NB);
  k_csort2<<<NB, 256, 0, stream>>>(tmp, bbase, rowptr, dinv, colx, N, NB, E);

  k_gemm<0><<<512, 256, 0, stream>>>(x, Wtg1, t, N);
  k_agg0<<<(N + 3) / 4, 256, 0, stream>>>(t, rowptr, colx, dinv, b1, h, N);
  k_gemm<1><<<512, 256, 0, stream>>>(h, Wtg2, t, N);
  int pwaves = (N + 15) / 16;
  k_aggp<<<(pwaves + 3) / 4, 256, 0, stream>>>(t, rowptr, colx, dinv, b2,
                                               bat, gb, N);

  k_mlp1<<<NGRAPH, 512, 0, stream>>>(gb, bat, N, Wm1, bm1, m1);
  k_mlp23<<<NGRAPH, 128, 0, stream>>>(m1, Wm2, bm2, Wm3, bm3, out);
}